// Round 1
// baseline (8721.133 us; speedup 1.0000x reference)
//
#include <hip/hip_runtime.h>

#define NNODES 100000
#define NEDGES 3200000
// NFEAT = NHID = 128, NCLASS = 64

__global__ __launch_bounds__(256) void deg_kernel(const int* __restrict__ dst,
                                                  float* __restrict__ deg) {
    int i = blockIdx.x * 256 + threadIdx.x;
    int stride = gridDim.x * 256;
    for (; i < NEDGES; i += stride) {
        atomicAdd(&deg[dst[i]], 1.0f);
    }
}

__global__ __launch_bounds__(256) void invd_kernel(float* __restrict__ deg) {
    int i = blockIdx.x * 256 + threadIdx.x;
    if (i < NNODES) deg[i] = 1.0f / fmaxf(deg[i], 1.0f);
}

// Y[r][c] = sum_k X[r][k] * W[k][c] (+ bias[c]), K = 128 fixed, OUT in {64,128}.
// W fully staged in LDS. 256 threads = 8 groups of 32 lanes; each group handles
// one row per iteration, each lane computes OUT/32 columns at stride 32
// (conflict-free LDS reads: lane -> bank lane%32).
template <int OUT>
__global__ __launch_bounds__(256) void gemm_k128(const float* __restrict__ X,
                                                 const float* __restrict__ W,
                                                 const float* __restrict__ bias,
                                                 float* __restrict__ Y, int nrows) {
    constexpr int J = OUT / 32;
    __shared__ float sW[128 * OUT];
    __shared__ float sX[8][128];
    const int tid = threadIdx.x;
    for (int i = tid * 4; i < 128 * OUT; i += 256 * 4) {
        *(float4*)&sW[i] = *(const float4*)&W[i];
    }
    const int lane = tid & 31;
    const int g = tid >> 5;
    float bv[J];
#pragma unroll
    for (int j = 0; j < J; ++j) bv[j] = bias ? bias[lane + 32 * j] : 0.0f;

    const int base = blockIdx.x * 64;
    for (int rr = 0; rr < 64; rr += 8) {
        const int r = base + rr + g;
        __syncthreads();  // protect sX before overwrite (also covers sW on first pass)
        if (r < nrows) {
            *(float4*)&sX[g][lane * 4] =
                *(const float4*)&X[(size_t)r * 128 + lane * 4];
        }
        __syncthreads();
        if (r < nrows) {
            float acc[J];
#pragma unroll
            for (int j = 0; j < J; ++j) acc[j] = bv[j];
#pragma unroll 4
            for (int k = 0; k < 128; ++k) {
                const float xv = sX[g][k];
#pragma unroll
                for (int j = 0; j < J; ++j) {
                    acc[j] = fmaf(xv, sW[k * OUT + lane + 32 * j], acc[j]);
                }
            }
#pragma unroll
            for (int j = 0; j < J; ++j) {
                Y[(size_t)r * OUT + lane + 32 * j] = acc[j];
            }
        }
    }
}

// out[dst] += invd[dst] * feat[src], F4 = feature_dim/4 chunks of float4 per edge.
template <int F4>
__global__ __launch_bounds__(256) void scatter_kernel(const int* __restrict__ src,
                                                      const int* __restrict__ dst,
                                                      const float* __restrict__ invd,
                                                      const float* __restrict__ feat,
                                                      float* __restrict__ out) {
    const long long total = (long long)NEDGES * F4;
    const long long stride = (long long)gridDim.x * 256;
    for (long long idx = (long long)blockIdx.x * 256 + threadIdx.x; idx < total;
         idx += stride) {
        const int e = (int)(idx / F4);   // F4 is a power of two -> shift
        const int q = (int)(idx & (F4 - 1));
        const int s = src[e];
        const int d = dst[e];
        const float w = invd[d];
        const float4 v = *(const float4*)&feat[(size_t)s * (F4 * 4) + q * 4];
        float* o = &out[(size_t)d * (F4 * 4) + q * 4];
        atomicAdd(o + 0, w * v.x);
        atomicAdd(o + 1, w * v.y);
        atomicAdd(o + 2, w * v.z);
        atomicAdd(o + 3, w * v.w);
    }
}

__global__ __launch_bounds__(256) void relu_kernel(float* __restrict__ h, long long n4) {
    const long long i = (long long)blockIdx.x * 256 + threadIdx.x;
    if (i < n4) {
        float4 v = ((float4*)h)[i];
        v.x = fmaxf(v.x, 0.0f);
        v.y = fmaxf(v.y, 0.0f);
        v.z = fmaxf(v.z, 0.0f);
        v.w = fmaxf(v.w, 0.0f);
        ((float4*)h)[i] = v;
    }
}

extern "C" void kernel_launch(void* const* d_in, const int* in_sizes, int n_in,
                              void* d_out, int out_size, void* d_ws, size_t ws_size,
                              hipStream_t stream) {
    const float* x   = (const float*)d_in[0];
    const int*   ei  = (const int*)d_in[1];
    const float* W1s = (const float*)d_in[2];
    const float* W1n = (const float*)d_in[3];
    const float* b1  = (const float*)d_in[4];
    const float* W2s = (const float*)d_in[5];
    const float* W2n = (const float*)d_in[6];
    const float* b2  = (const float*)d_in[7];
    float* out = (float*)d_out;

    const int* src = ei;           // edge_index row 0
    const int* dst = ei + NEDGES;  // edge_index row 1

    float* ws   = (float*)d_ws;
    float* invd = ws;                              // N floats (deg -> invd in place)
    float* xn   = invd + 100032;                   // N*128 (reused as hn for layer 2)
    float* h    = xn + (size_t)NNODES * 128;       // N*128
    float* hn   = xn;                              // reuse: xn dead after scatter1

    // degree -> inverse degree
    hipMemsetAsync(invd, 0, NNODES * sizeof(float), stream);
    deg_kernel<<<2048, 256, 0, stream>>>(dst, invd);
    invd_kernel<<<(NNODES + 255) / 256, 256, 0, stream>>>(invd);

    // layer 1: h = x@W1_self + b1 ; xn = x@W1_neigh
    gemm_k128<128><<<(NNODES + 63) / 64, 256, 0, stream>>>(x, W1s, b1, h, NNODES);
    gemm_k128<128><<<(NNODES + 63) / 64, 256, 0, stream>>>(x, W1n, nullptr, xn, NNODES);
    // h[dst] += invd[dst] * xn[src]
    scatter_kernel<32><<<8192, 256, 0, stream>>>(src, dst, invd, xn, h);
    relu_kernel<<<(int)((NNODES * 128LL / 4 + 255) / 256), 256, 0, stream>>>(
        h, NNODES * 128LL / 4);

    // layer 2: out = h@W2_self + b2 ; hn = h@W2_neigh ; out[dst] += invd[dst]*hn[src]
    gemm_k128<64><<<(NNODES + 63) / 64, 256, 0, stream>>>(h, W2s, b2, out, NNODES);
    gemm_k128<64><<<(NNODES + 63) / 64, 256, 0, stream>>>(h, W2n, nullptr, hn, NNODES);
    scatter_kernel<16><<<8192, 256, 0, stream>>>(src, dst, invd, hn, out);
}

// Round 2
// 1240.894 us; speedup vs baseline: 7.0281x; 7.0281x over previous
//
#include <hip/hip_runtime.h>

#define NNODES 100000
#define NEDGES 3200000
#define NB_SCAN 98   // ceil(NNODES/1024)
// NFEAT = NHID = 128, NCLASS = 64

// ---------- degree (int atomics) ----------
__global__ __launch_bounds__(256) void deg_kernel(const int* __restrict__ dst,
                                                  int* __restrict__ deg) {
    int i = blockIdx.x * 256 + threadIdx.x;
    int stride = gridDim.x * 256;
    for (; i < NEDGES; i += stride) {
        atomicAdd(&deg[dst[i]], 1);
    }
}

// ---------- prefix sum (exclusive) over deg -> rs, 1024 elems/block ----------
__global__ __launch_bounds__(256) void scan_chunk(const int* __restrict__ deg,
                                                  int* __restrict__ rs,
                                                  int* __restrict__ bsum) {
    __shared__ int s[256];
    const int tid = threadIdx.x;
    const int base = blockIdx.x * 1024 + tid * 4;
    int v[4];
#pragma unroll
    for (int j = 0; j < 4; ++j) v[j] = (base + j < NNODES) ? deg[base + j] : 0;
    const int tsum = v[0] + v[1] + v[2] + v[3];
    s[tid] = tsum;
    __syncthreads();
    for (int ofs = 1; ofs < 256; ofs <<= 1) {
        int t = (tid >= ofs) ? s[tid - ofs] : 0;
        __syncthreads();
        if (tid >= ofs) s[tid] += t;
        __syncthreads();
    }
    const int excl = s[tid] - tsum;
    int run = excl;
#pragma unroll
    for (int j = 0; j < 4; ++j) {
        if (base + j < NNODES) rs[base + j] = run;
        run += v[j];
    }
    if (tid == 255) bsum[blockIdx.x] = s[255];
}

__global__ __launch_bounds__(128) void scan_bsums(const int* __restrict__ bsum,
                                                  int* __restrict__ boffs) {
    __shared__ int s[128];
    const int tid = threadIdx.x;
    const int v = (tid < NB_SCAN) ? bsum[tid] : 0;
    s[tid] = v;
    __syncthreads();
    for (int ofs = 1; ofs < 128; ofs <<= 1) {
        int t = (tid >= ofs) ? s[tid - ofs] : 0;
        __syncthreads();
        if (tid >= ofs) s[tid] += t;
        __syncthreads();
    }
    boffs[tid] = s[tid] - v;  // exclusive
}

// rs += boffs, cursor = rs, invd = 1/max(deg,1), rs[N] = E
__global__ __launch_bounds__(256) void finalize_kernel(int* __restrict__ rs,
                                                       const int* __restrict__ boffs,
                                                       int* __restrict__ cursor,
                                                       const int* __restrict__ deg,
                                                       float* __restrict__ invd) {
    const int i = blockIdx.x * 256 + threadIdx.x;
    if (i < NNODES) {
        const int v = rs[i] + boffs[i >> 10];
        rs[i] = v;
        cursor[i] = v;
        invd[i] = 1.0f / fmaxf((float)deg[i], 1.0f);
    }
    if (i == 0) rs[NNODES] = NEDGES;
}

// ---------- CSR bucket fill: 1 int atomic per edge ----------
__global__ __launch_bounds__(256) void fill_kernel(const int* __restrict__ src,
                                                   const int* __restrict__ dst,
                                                   int* __restrict__ cursor,
                                                   int* __restrict__ ebuf) {
    int i = blockIdx.x * 256 + threadIdx.x;
    int stride = gridDim.x * 256;
    for (; i < NEDGES; i += stride) {
        const int pos = atomicAdd(&cursor[dst[i]], 1);
        ebuf[pos] = src[i];
    }
}

// ---------- dense GEMM, K=128, OUT in {64,128} ----------
template <int OUT>
__global__ __launch_bounds__(256) void gemm_k128(const float* __restrict__ X,
                                                 const float* __restrict__ W,
                                                 const float* __restrict__ bias,
                                                 float* __restrict__ Y, int nrows) {
    constexpr int J = OUT / 32;
    __shared__ float sW[128 * OUT];
    __shared__ float sX[8][128];
    const int tid = threadIdx.x;
    for (int i = tid * 4; i < 128 * OUT; i += 256 * 4) {
        *(float4*)&sW[i] = *(const float4*)&W[i];
    }
    const int lane = tid & 31;
    const int g = tid >> 5;
    float bv[J];
#pragma unroll
    for (int j = 0; j < J; ++j) bv[j] = bias ? bias[lane + 32 * j] : 0.0f;

    const int base = blockIdx.x * 64;
    for (int rr = 0; rr < 64; rr += 8) {
        const int r = base + rr + g;
        __syncthreads();
        if (r < nrows) {
            *(float4*)&sX[g][lane * 4] =
                *(const float4*)&X[(size_t)r * 128 + lane * 4];
        }
        __syncthreads();
        if (r < nrows) {
            float acc[J];
#pragma unroll
            for (int j = 0; j < J; ++j) acc[j] = bv[j];
#pragma unroll 4
            for (int k = 0; k < 128; ++k) {
                const float xv = sX[g][k];
#pragma unroll
                for (int j = 0; j < J; ++j) {
                    acc[j] = fmaf(xv, sW[k * OUT + lane + 32 * j], acc[j]);
                }
            }
#pragma unroll
            for (int j = 0; j < J; ++j) {
                Y[(size_t)r * OUT + lane + 32 * j] = acc[j];
            }
        }
    }
}

// ---------- layer-1 aggregation: h[d] = relu(h[d] + invd[d]*sum(feat[src])) ----------
// one 64-lane wave per node, float2 per lane (128 cols)
__global__ __launch_bounds__(256) void agg1_kernel(const int* __restrict__ rs,
                                                   const int* __restrict__ ebuf,
                                                   const float* __restrict__ invd,
                                                   const float* __restrict__ feat,
                                                   float* __restrict__ h) {
    const int node = blockIdx.x * 4 + (threadIdx.x >> 6);
    if (node >= NNODES) return;
    const int lane = threadIdx.x & 63;
    const int beg = rs[node];
    const int end = rs[node + 1];
    const float* fp = feat + lane * 2;
    float ax = 0.0f, ay = 0.0f;
    int i = beg;
    for (; i + 1 < end; i += 2) {
        const int s0 = ebuf[i];
        const int s1 = ebuf[i + 1];
        const float2 v0 = *(const float2*)&fp[(size_t)s0 * 128];
        const float2 v1 = *(const float2*)&fp[(size_t)s1 * 128];
        ax += v0.x + v1.x;
        ay += v0.y + v1.y;
    }
    if (i < end) {
        const int s = ebuf[i];
        const float2 v = *(const float2*)&fp[(size_t)s * 128];
        ax += v.x;
        ay += v.y;
    }
    const float w = invd[node];
    float* hp = &h[(size_t)node * 128 + lane * 2];
    float2 hv = *(float2*)hp;
    hv.x = fmaxf(fmaf(w, ax, hv.x), 0.0f);
    hv.y = fmaxf(fmaf(w, ay, hv.y), 0.0f);
    *(float2*)hp = hv;
}

// ---------- layer-2 aggregation: out[d] += invd[d]*sum(feat[src]), 64 cols ----------
__global__ __launch_bounds__(256) void agg2_kernel(const int* __restrict__ rs,
                                                   const int* __restrict__ ebuf,
                                                   const float* __restrict__ invd,
                                                   const float* __restrict__ feat,
                                                   float* __restrict__ out) {
    const int node = blockIdx.x * 4 + (threadIdx.x >> 6);
    if (node >= NNODES) return;
    const int lane = threadIdx.x & 63;
    const int beg = rs[node];
    const int end = rs[node + 1];
    const float* fp = feat + lane;
    float acc = 0.0f;
    int i = beg;
    for (; i + 1 < end; i += 2) {
        const int s0 = ebuf[i];
        const int s1 = ebuf[i + 1];
        acc += fp[(size_t)s0 * 64] + fp[(size_t)s1 * 64];
    }
    if (i < end) acc += fp[(size_t)ebuf[i] * 64];
    const float w = invd[node];
    out[(size_t)node * 64 + lane] = fmaf(w, acc, out[(size_t)node * 64 + lane]);
}

extern "C" void kernel_launch(void* const* d_in, const int* in_sizes, int n_in,
                              void* d_out, int out_size, void* d_ws, size_t ws_size,
                              hipStream_t stream) {
    const float* x   = (const float*)d_in[0];
    const int*   ei  = (const int*)d_in[1];
    const float* W1s = (const float*)d_in[2];
    const float* W1n = (const float*)d_in[3];
    const float* b1  = (const float*)d_in[4];
    const float* W2s = (const float*)d_in[5];
    const float* W2n = (const float*)d_in[6];
    const float* b2  = (const float*)d_in[7];
    float* out = (float*)d_out;

    const int* src = ei;           // edge_index row 0
    const int* dst = ei + NEDGES;  // edge_index row 1

    // workspace carve-up (4B elements)
    char* base = (char*)d_ws;
    int*   deg    = (int*)base;                          // 100,096
    float* invd   = (float*)(base + 100096 * 4);         // 100,096
    int*   rs     = (int*)(base + 200192 * 4);           // 100,352 (needs N+1)
    int*   cursor = (int*)(base + 300544 * 4);           // 100,096
    int*   bsum   = (int*)(base + 400640 * 4);           // 128
    int*   boffs  = (int*)(base + 400768 * 4);           // 128
    int*   ebuf   = (int*)(base + 400896 * 4);           // 3,200,000
    float* xn     = (float*)(base + 3600896LL * 4);      // 12,800,000 (reused as hn)
    float* h      = (float*)(base + 16400896LL * 4);     // 12,800,000
    float* hn     = xn;

    // ---- CSR build (reused by both layers) ----
    hipMemsetAsync(deg, 0, NNODES * sizeof(int), stream);
    deg_kernel<<<2048, 256, 0, stream>>>(dst, deg);
    scan_chunk<<<NB_SCAN, 256, 0, stream>>>(deg, rs, bsum);
    scan_bsums<<<1, 128, 0, stream>>>(bsum, boffs);
    finalize_kernel<<<(NNODES + 255) / 256, 256, 0, stream>>>(rs, boffs, cursor, deg, invd);
    fill_kernel<<<2048, 256, 0, stream>>>(src, dst, cursor, ebuf);

    // ---- layer 1 ----
    gemm_k128<128><<<(NNODES + 63) / 64, 256, 0, stream>>>(x, W1s, b1, h, NNODES);
    gemm_k128<128><<<(NNODES + 63) / 64, 256, 0, stream>>>(x, W1n, nullptr, xn, NNODES);
    agg1_kernel<<<(NNODES + 3) / 4, 256, 0, stream>>>(rs, ebuf, invd, xn, h);

    // ---- layer 2 ----
    gemm_k128<64><<<(NNODES + 63) / 64, 256, 0, stream>>>(h, W2s, b2, out, NNODES);
    gemm_k128<64><<<(NNODES + 63) / 64, 256, 0, stream>>>(h, W2n, nullptr, hn, NNODES);
    agg2_kernel<<<(NNODES + 3) / 4, 256, 0, stream>>>(rs, ebuf, invd, hn, out);
}

// Round 3
// 741.309 us; speedup vs baseline: 11.7645x; 1.6739x over previous
//
#include <hip/hip_runtime.h>

#define NNODES 100000
#define NEDGES 3200000
#define NB_SCAN 98      // ceil(NNODES/1024)
#define G1BLOCKS 3125   // NNODES/32 exactly
#define FILLQ 2084      // fill blocks in mega1 (one per quad)

// ---------- degree (int atomics) ----------
__global__ __launch_bounds__(256) void deg_kernel(const int* __restrict__ dst,
                                                  int* __restrict__ deg) {
    int i = blockIdx.x * 256 + threadIdx.x;
    int stride = gridDim.x * 256;
    for (; i < NEDGES; i += stride) {
        atomicAdd(&deg[dst[i]], 1);
    }
}

// ---------- prefix sum (exclusive) over deg -> rs ----------
__global__ __launch_bounds__(256) void scan_chunk(const int* __restrict__ deg,
                                                  int* __restrict__ rs,
                                                  int* __restrict__ bsum) {
    __shared__ int s[256];
    const int tid = threadIdx.x;
    const int base = blockIdx.x * 1024 + tid * 4;
    int v[4];
#pragma unroll
    for (int j = 0; j < 4; ++j) v[j] = (base + j < NNODES) ? deg[base + j] : 0;
    const int tsum = v[0] + v[1] + v[2] + v[3];
    s[tid] = tsum;
    __syncthreads();
    for (int ofs = 1; ofs < 256; ofs <<= 1) {
        int t = (tid >= ofs) ? s[tid - ofs] : 0;
        __syncthreads();
        if (tid >= ofs) s[tid] += t;
        __syncthreads();
    }
    const int excl = s[tid] - tsum;
    int run = excl;
#pragma unroll
    for (int j = 0; j < 4; ++j) {
        if (base + j < NNODES) rs[base + j] = run;
        run += v[j];
    }
    if (tid == 255) bsum[blockIdx.x] = s[255];
}

__global__ __launch_bounds__(128) void scan_bsums(const int* __restrict__ bsum,
                                                  int* __restrict__ boffs) {
    __shared__ int s[128];
    const int tid = threadIdx.x;
    const int v = (tid < NB_SCAN) ? bsum[tid] : 0;
    s[tid] = v;
    __syncthreads();
    for (int ofs = 1; ofs < 128; ofs <<= 1) {
        int t = (tid >= ofs) ? s[tid - ofs] : 0;
        __syncthreads();
        if (tid >= ofs) s[tid] += t;
        __syncthreads();
    }
    boffs[tid] = s[tid] - v;  // exclusive
}

__global__ __launch_bounds__(256) void finalize_kernel(int* __restrict__ rs,
                                                       const int* __restrict__ boffs,
                                                       int* __restrict__ cursor,
                                                       const int* __restrict__ deg,
                                                       float* __restrict__ invd) {
    const int i = blockIdx.x * 256 + threadIdx.x;
    if (i < NNODES) {
        const int v = rs[i] + boffs[i >> 10];
        rs[i] = v;
        cursor[i] = v;
        invd[i] = 1.0f / fmaxf((float)deg[i], 1.0f);
    }
    if (i == 0) rs[NNODES] = NEDGES;
}

// ---------- mega1: CSR fill (1/4 of blocks) co-scheduled with layer-1 GEMMs ----------
// GEMM: 32 rows/block, 128 cols; thread = 4 rows x 4 cols; sW float4 reads
// conflict-free, sX reads half-wave-broadcast (2-way = free).
__global__ __launch_bounds__(256) void mega1_kernel(
    const float* __restrict__ x, const float* __restrict__ W1s,
    const float* __restrict__ W1n, const float* __restrict__ b1,
    float* __restrict__ h, float* __restrict__ xn,
    const int* __restrict__ src, const int* __restrict__ dst,
    int* __restrict__ cursor, int* __restrict__ ebuf) {
    __shared__ float sW[128 * 128];
    __shared__ float sX[32][128];
    const int bid = blockIdx.x;
    const int tid = threadIdx.x;
    if ((bid & 3) == 3) {
        // ---- fill branch: 1 int atomic + 1 scattered 4B write per edge ----
        int i = (bid >> 2) * 256 + tid;
        for (; i < NEDGES; i += FILLQ * 256) {
            const int pos = atomicAdd(&cursor[dst[i]], 1);
            ebuf[pos] = src[i];
        }
        return;
    }
    const int g = (bid >> 2) * 3 + (bid & 3);
    if (g >= 2 * G1BLOCKS) return;
    const bool self = g < G1BLOCKS;
    const float* __restrict__ W = self ? W1s : W1n;
    float* __restrict__ Y = self ? h : xn;
    const int rowbase = (self ? g : g - G1BLOCKS) * 32;

    for (int idx = tid * 4; idx < 128 * 128; idx += 1024)
        *(float4*)&sW[idx] = *(const float4*)&W[idx];
    for (int idx = tid * 4; idx < 32 * 128; idx += 1024) {
        const int r = rowbase + (idx >> 7);
        *(float4*)&sX[0][idx] = *(const float4*)&x[(size_t)r * 128 + (idx & 127)];
    }
    __syncthreads();

    const int c4 = (tid & 31) * 4;
    const int r0 = (tid >> 5) * 4;
    float acc[4][4];
    if (self) {
        const float4 bv = *(const float4*)&b1[c4];
#pragma unroll
        for (int i = 0; i < 4; ++i) {
            acc[i][0] = bv.x; acc[i][1] = bv.y; acc[i][2] = bv.z; acc[i][3] = bv.w;
        }
    } else {
#pragma unroll
        for (int i = 0; i < 4; ++i)
#pragma unroll
            for (int j = 0; j < 4; ++j) acc[i][j] = 0.0f;
    }
#pragma unroll 4
    for (int k = 0; k < 128; ++k) {
        const float4 wv = *(const float4*)&sW[k * 128 + c4];
        const float x0 = sX[r0 + 0][k];
        const float x1 = sX[r0 + 1][k];
        const float x2 = sX[r0 + 2][k];
        const float x3 = sX[r0 + 3][k];
        acc[0][0] = fmaf(x0, wv.x, acc[0][0]); acc[0][1] = fmaf(x0, wv.y, acc[0][1]);
        acc[0][2] = fmaf(x0, wv.z, acc[0][2]); acc[0][3] = fmaf(x0, wv.w, acc[0][3]);
        acc[1][0] = fmaf(x1, wv.x, acc[1][0]); acc[1][1] = fmaf(x1, wv.y, acc[1][1]);
        acc[1][2] = fmaf(x1, wv.z, acc[1][2]); acc[1][3] = fmaf(x1, wv.w, acc[1][3]);
        acc[2][0] = fmaf(x2, wv.x, acc[2][0]); acc[2][1] = fmaf(x2, wv.y, acc[2][1]);
        acc[2][2] = fmaf(x2, wv.z, acc[2][2]); acc[2][3] = fmaf(x2, wv.w, acc[2][3]);
        acc[3][0] = fmaf(x3, wv.x, acc[3][0]); acc[3][1] = fmaf(x3, wv.y, acc[3][1]);
        acc[3][2] = fmaf(x3, wv.z, acc[3][2]); acc[3][3] = fmaf(x3, wv.w, acc[3][3]);
    }
#pragma unroll
    for (int i = 0; i < 4; ++i) {
        float4 o;
        o.x = acc[i][0]; o.y = acc[i][1]; o.z = acc[i][2]; o.w = acc[i][3];
        *(float4*)&Y[(size_t)(rowbase + r0 + i) * 128 + c4] = o;
    }
}

// ---------- layer-2 dual GEMM: out = h@W2s + b2 ; hn = h@W2n (one pass over h) ----------
__global__ __launch_bounds__(256) void gemm2_dual_kernel(
    const float* __restrict__ hbuf, const float* __restrict__ W2s,
    const float* __restrict__ W2n, const float* __restrict__ b2,
    float* __restrict__ out, float* __restrict__ hn) {
    __shared__ float sW[128 * 128];
    __shared__ float sX[32][128];
    const int tid = threadIdx.x;
    const int rowbase = blockIdx.x * 32;
    for (int idx = tid * 4; idx < 128 * 128; idx += 1024) {
        const int k = idx >> 7, col = idx & 127;
        const float* srcp = (col < 64) ? &W2s[k * 64 + col] : &W2n[k * 64 + (col - 64)];
        *(float4*)&sW[idx] = *(const float4*)srcp;
    }
    for (int idx = tid * 4; idx < 32 * 128; idx += 1024) {
        const int r = rowbase + (idx >> 7);
        *(float4*)&sX[0][idx] = *(const float4*)&hbuf[(size_t)r * 128 + (idx & 127)];
    }
    __syncthreads();

    const int c = tid & 31;
    const int c4 = c * 4;
    const int r0 = (tid >> 5) * 4;
    float acc[4][4];
    if (c < 16) {
        const float4 bv = *(const float4*)&b2[c4];
#pragma unroll
        for (int i = 0; i < 4; ++i) {
            acc[i][0] = bv.x; acc[i][1] = bv.y; acc[i][2] = bv.z; acc[i][3] = bv.w;
        }
    } else {
#pragma unroll
        for (int i = 0; i < 4; ++i)
#pragma unroll
            for (int j = 0; j < 4; ++j) acc[i][j] = 0.0f;
    }
#pragma unroll 4
    for (int k = 0; k < 128; ++k) {
        const float4 wv = *(const float4*)&sW[k * 128 + c4];
        const float x0 = sX[r0 + 0][k];
        const float x1 = sX[r0 + 1][k];
        const float x2 = sX[r0 + 2][k];
        const float x3 = sX[r0 + 3][k];
        acc[0][0] = fmaf(x0, wv.x, acc[0][0]); acc[0][1] = fmaf(x0, wv.y, acc[0][1]);
        acc[0][2] = fmaf(x0, wv.z, acc[0][2]); acc[0][3] = fmaf(x0, wv.w, acc[0][3]);
        acc[1][0] = fmaf(x1, wv.x, acc[1][0]); acc[1][1] = fmaf(x1, wv.y, acc[1][1]);
        acc[1][2] = fmaf(x1, wv.z, acc[1][2]); acc[1][3] = fmaf(x1, wv.w, acc[1][3]);
        acc[2][0] = fmaf(x2, wv.x, acc[2][0]); acc[2][1] = fmaf(x2, wv.y, acc[2][1]);
        acc[2][2] = fmaf(x2, wv.z, acc[2][2]); acc[2][3] = fmaf(x2, wv.w, acc[2][3]);
        acc[3][0] = fmaf(x3, wv.x, acc[3][0]); acc[3][1] = fmaf(x3, wv.y, acc[3][1]);
        acc[3][2] = fmaf(x3, wv.z, acc[3][2]); acc[3][3] = fmaf(x3, wv.w, acc[3][3]);
    }
#pragma unroll
    for (int i = 0; i < 4; ++i) {
        const int row = rowbase + r0 + i;
        float4 o;
        o.x = acc[i][0]; o.y = acc[i][1]; o.z = acc[i][2]; o.w = acc[i][3];
        if (c < 16) {
            *(float4*)&out[(size_t)row * 64 + c4] = o;
        } else {
            *(float4*)&hn[(size_t)row * 64 + (c4 - 64)] = o;
        }
    }
}

// ---------- layer-1 aggregation: h[d] = relu(h[d] + invd[d]*sum(xn[src])) ----------
__global__ __launch_bounds__(256) void agg1_kernel(const int* __restrict__ rs,
                                                   const int* __restrict__ ebuf,
                                                   const float* __restrict__ invd,
                                                   const float* __restrict__ feat,
                                                   float* __restrict__ h) {
    const int node = blockIdx.x * 4 + (threadIdx.x >> 6);
    if (node >= NNODES) return;
    const int lane = threadIdx.x & 63;
    const int beg = rs[node];
    const int end = rs[node + 1];
    const float* fp = feat + lane * 2;
    float ax = 0.0f, ay = 0.0f;
    int i = beg;
    for (; i + 3 < end; i += 4) {
        const int s0 = ebuf[i], s1 = ebuf[i + 1], s2 = ebuf[i + 2], s3 = ebuf[i + 3];
        const float2 v0 = *(const float2*)&fp[(size_t)s0 * 128];
        const float2 v1 = *(const float2*)&fp[(size_t)s1 * 128];
        const float2 v2 = *(const float2*)&fp[(size_t)s2 * 128];
        const float2 v3 = *(const float2*)&fp[(size_t)s3 * 128];
        ax += (v0.x + v1.x) + (v2.x + v3.x);
        ay += (v0.y + v1.y) + (v2.y + v3.y);
    }
    for (; i < end; ++i) {
        const float2 v = *(const float2*)&fp[(size_t)ebuf[i] * 128];
        ax += v.x;
        ay += v.y;
    }
    const float w = invd[node];
    float* hp = &h[(size_t)node * 128 + lane * 2];
    float2 hv = *(float2*)hp;
    hv.x = fmaxf(fmaf(w, ax, hv.x), 0.0f);
    hv.y = fmaxf(fmaf(w, ay, hv.y), 0.0f);
    *(float2*)hp = hv;
}

// ---------- layer-2 aggregation: out[d] += invd[d]*sum(hn[src]) ----------
__global__ __launch_bounds__(256) void agg2_kernel(const int* __restrict__ rs,
                                                   const int* __restrict__ ebuf,
                                                   const float* __restrict__ invd,
                                                   const float* __restrict__ feat,
                                                   float* __restrict__ out) {
    const int node = blockIdx.x * 4 + (threadIdx.x >> 6);
    if (node >= NNODES) return;
    const int lane = threadIdx.x & 63;
    const int beg = rs[node];
    const int end = rs[node + 1];
    const float* fp = feat + lane;
    float acc = 0.0f;
    int i = beg;
    for (; i + 3 < end; i += 4) {
        const int s0 = ebuf[i], s1 = ebuf[i + 1], s2 = ebuf[i + 2], s3 = ebuf[i + 3];
        const float a0 = fp[(size_t)s0 * 64];
        const float a1 = fp[(size_t)s1 * 64];
        const float a2 = fp[(size_t)s2 * 64];
        const float a3 = fp[(size_t)s3 * 64];
        acc += (a0 + a1) + (a2 + a3);
    }
    for (; i < end; ++i) acc += fp[(size_t)ebuf[i] * 64];
    const float w = invd[node];
    out[(size_t)node * 64 + lane] = fmaf(w, acc, out[(size_t)node * 64 + lane]);
}

extern "C" void kernel_launch(void* const* d_in, const int* in_sizes, int n_in,
                              void* d_out, int out_size, void* d_ws, size_t ws_size,
                              hipStream_t stream) {
    const float* x   = (const float*)d_in[0];
    const int*   ei  = (const int*)d_in[1];
    const float* W1s = (const float*)d_in[2];
    const float* W1n = (const float*)d_in[3];
    const float* b1  = (const float*)d_in[4];
    const float* W2s = (const float*)d_in[5];
    const float* W2n = (const float*)d_in[6];
    const float* b2  = (const float*)d_in[7];
    float* out = (float*)d_out;

    const int* src = ei;           // edge_index row 0
    const int* dst = ei + NEDGES;  // edge_index row 1

    // workspace carve-up (4B elements)
    char* base = (char*)d_ws;
    int*   deg    = (int*)base;                          // 100,096
    float* invd   = (float*)(base + 100096 * 4);         // 100,096
    int*   rs     = (int*)(base + 200192 * 4);           // 100,352 (N+1)
    int*   cursor = (int*)(base + 300544 * 4);           // 100,096
    int*   bsum   = (int*)(base + 400640 * 4);           // 128
    int*   boffs  = (int*)(base + 400768 * 4);           // 128
    int*   ebuf   = (int*)(base + 400896 * 4);           // 3,200,000
    float* xn     = (float*)(base + 3600896LL * 4);      // 12,800,000 (reused as hn)
    float* h      = (float*)(base + 16400896LL * 4);     // 12,800,000
    float* hn     = xn;

    // ---- CSR build prologue ----
    hipMemsetAsync(deg, 0, NNODES * sizeof(int), stream);
    deg_kernel<<<2048, 256, 0, stream>>>(dst, deg);
    scan_chunk<<<NB_SCAN, 256, 0, stream>>>(deg, rs, bsum);
    scan_bsums<<<1, 128, 0, stream>>>(bsum, boffs);
    finalize_kernel<<<(NNODES + 255) / 256, 256, 0, stream>>>(rs, boffs, cursor, deg, invd);

    // ---- CSR fill co-scheduled with layer-1 GEMMs ----
    mega1_kernel<<<FILLQ * 4, 256, 0, stream>>>(x, W1s, W1n, b1, h, xn, src, dst,
                                                cursor, ebuf);
    agg1_kernel<<<(NNODES + 3) / 4, 256, 0, stream>>>(rs, ebuf, invd, xn, h);

    // ---- layer 2 ----
    gemm2_dual_kernel<<<G1BLOCKS, 256, 0, stream>>>(h, W2s, W2n, b2, out, hn);
    agg2_kernel<<<(NNODES + 3) / 4, 256, 0, stream>>>(rs, ebuf, invd, hn, out);
}

// Round 4
// 578.538 us; speedup vs baseline: 15.0744x; 1.2813x over previous
//
#include <hip/hip_runtime.h>

#define NNODES 100000
#define NEDGES 3200000
#define NB_SCAN 98      // ceil(NNODES/1024)
#define G1BLOCKS 3125   // NNODES/32 exactly
#define FILLQ 2084      // fill blocks in mega1 (one per quad)

typedef unsigned int uint;
typedef unsigned short ushort;

// ---- bf16 pack/unpack (RNE) ----
__device__ inline uint pack_bf2(float a, float b) {
    uint ua = __float_as_uint(a);
    uint ub = __float_as_uint(b);
    ua = (ua + 0x7FFFu + ((ua >> 16) & 1u)) >> 16;
    ub = (ub + 0x7FFFu + ((ub >> 16) & 1u)) >> 16;
    return ua | (ub << 16);
}
__device__ inline float2 unpack_bf2(uint v) {
    float2 r;
    r.x = __uint_as_float(v << 16);
    r.y = __uint_as_float(v & 0xFFFF0000u);
    return r;
}

// ---------- degree (int atomics) ----------
__global__ __launch_bounds__(256) void deg_kernel(const int* __restrict__ dst,
                                                  int* __restrict__ deg) {
    int i = blockIdx.x * 256 + threadIdx.x;
    int stride = gridDim.x * 256;
    for (; i < NEDGES; i += stride) {
        atomicAdd(&deg[dst[i]], 1);
    }
}

// ---------- prefix sum (exclusive) over deg -> rs ----------
__global__ __launch_bounds__(256) void scan_chunk(const int* __restrict__ deg,
                                                  int* __restrict__ rs,
                                                  int* __restrict__ bsum) {
    __shared__ int s[256];
    const int tid = threadIdx.x;
    const int base = blockIdx.x * 1024 + tid * 4;
    int v[4];
#pragma unroll
    for (int j = 0; j < 4; ++j) v[j] = (base + j < NNODES) ? deg[base + j] : 0;
    const int tsum = v[0] + v[1] + v[2] + v[3];
    s[tid] = tsum;
    __syncthreads();
    for (int ofs = 1; ofs < 256; ofs <<= 1) {
        int t = (tid >= ofs) ? s[tid - ofs] : 0;
        __syncthreads();
        if (tid >= ofs) s[tid] += t;
        __syncthreads();
    }
    const int excl = s[tid] - tsum;
    int run = excl;
#pragma unroll
    for (int j = 0; j < 4; ++j) {
        if (base + j < NNODES) rs[base + j] = run;
        run += v[j];
    }
    if (tid == 255) bsum[blockIdx.x] = s[255];
}

__global__ __launch_bounds__(128) void scan_bsums(const int* __restrict__ bsum,
                                                  int* __restrict__ boffs) {
    __shared__ int s[128];
    const int tid = threadIdx.x;
    const int v = (tid < NB_SCAN) ? bsum[tid] : 0;
    s[tid] = v;
    __syncthreads();
    for (int ofs = 1; ofs < 128; ofs <<= 1) {
        int t = (tid >= ofs) ? s[tid - ofs] : 0;
        __syncthreads();
        if (tid >= ofs) s[tid] += t;
        __syncthreads();
    }
    boffs[tid] = s[tid] - v;  // exclusive
}

__global__ __launch_bounds__(256) void finalize_kernel(int* __restrict__ rs,
                                                       const int* __restrict__ boffs,
                                                       int* __restrict__ cursor,
                                                       const int* __restrict__ deg,
                                                       float* __restrict__ invd) {
    const int i = blockIdx.x * 256 + threadIdx.x;
    if (i < NNODES) {
        const int v = rs[i] + boffs[i >> 10];
        rs[i] = v;
        cursor[i] = v;
        invd[i] = 1.0f / fmaxf((float)deg[i], 1.0f);
    }
    if (i == 0) rs[NNODES] = NEDGES;
}

// ---------- mega1: CSR fill co-scheduled with layer-1 GEMMs (bf16 outputs) ----------
__global__ __launch_bounds__(256) void mega1_kernel(
    const float* __restrict__ x, const float* __restrict__ W1s,
    const float* __restrict__ W1n, const float* __restrict__ b1,
    ushort* __restrict__ hbf, ushort* __restrict__ xnbf,
    const int* __restrict__ src, const int* __restrict__ dst,
    int* __restrict__ cursor, int* __restrict__ ebuf) {
    __shared__ float sW[128 * 128];
    __shared__ float sX[32][128];
    const int bid = blockIdx.x;
    const int tid = threadIdx.x;
    if ((bid & 3) == 3) {
        // ---- fill branch: 1 int atomic + 1 scattered 4B write per edge ----
        int i = (bid >> 2) * 256 + tid;
        for (; i < NEDGES; i += FILLQ * 256) {
            const int pos = atomicAdd(&cursor[dst[i]], 1);
            ebuf[pos] = src[i];
        }
        return;
    }
    const int g = (bid >> 2) * 3 + (bid & 3);
    if (g >= 2 * G1BLOCKS) return;
    const bool self = g < G1BLOCKS;
    const float* __restrict__ W = self ? W1s : W1n;
    ushort* __restrict__ Y = self ? hbf : xnbf;
    const int rowbase = (self ? g : g - G1BLOCKS) * 32;

    for (int idx = tid * 4; idx < 128 * 128; idx += 1024)
        *(float4*)&sW[idx] = *(const float4*)&W[idx];
    for (int idx = tid * 4; idx < 32 * 128; idx += 1024) {
        const int r = rowbase + (idx >> 7);
        *(float4*)&sX[0][idx] = *(const float4*)&x[(size_t)r * 128 + (idx & 127)];
    }
    __syncthreads();

    const int c4 = (tid & 31) * 4;
    const int r0 = (tid >> 5) * 4;
    float acc[4][4];
    if (self) {
        const float4 bv = *(const float4*)&b1[c4];
#pragma unroll
        for (int i = 0; i < 4; ++i) {
            acc[i][0] = bv.x; acc[i][1] = bv.y; acc[i][2] = bv.z; acc[i][3] = bv.w;
        }
    } else {
#pragma unroll
        for (int i = 0; i < 4; ++i)
#pragma unroll
            for (int j = 0; j < 4; ++j) acc[i][j] = 0.0f;
    }
#pragma unroll 4
    for (int k = 0; k < 128; ++k) {
        const float4 wv = *(const float4*)&sW[k * 128 + c4];
        const float x0 = sX[r0 + 0][k];
        const float x1 = sX[r0 + 1][k];
        const float x2 = sX[r0 + 2][k];
        const float x3 = sX[r0 + 3][k];
        acc[0][0] = fmaf(x0, wv.x, acc[0][0]); acc[0][1] = fmaf(x0, wv.y, acc[0][1]);
        acc[0][2] = fmaf(x0, wv.z, acc[0][2]); acc[0][3] = fmaf(x0, wv.w, acc[0][3]);
        acc[1][0] = fmaf(x1, wv.x, acc[1][0]); acc[1][1] = fmaf(x1, wv.y, acc[1][1]);
        acc[1][2] = fmaf(x1, wv.z, acc[1][2]); acc[1][3] = fmaf(x1, wv.w, acc[1][3]);
        acc[2][0] = fmaf(x2, wv.x, acc[2][0]); acc[2][1] = fmaf(x2, wv.y, acc[2][1]);
        acc[2][2] = fmaf(x2, wv.z, acc[2][2]); acc[2][3] = fmaf(x2, wv.w, acc[2][3]);
        acc[3][0] = fmaf(x3, wv.x, acc[3][0]); acc[3][1] = fmaf(x3, wv.y, acc[3][1]);
        acc[3][2] = fmaf(x3, wv.z, acc[3][2]); acc[3][3] = fmaf(x3, wv.w, acc[3][3]);
    }
#pragma unroll
    for (int i = 0; i < 4; ++i) {
        uint2 o;
        o.x = pack_bf2(acc[i][0], acc[i][1]);
        o.y = pack_bf2(acc[i][2], acc[i][3]);
        *(uint2*)&Y[(size_t)(rowbase + r0 + i) * 128 + c4] = o;
    }
}

// ---------- layer-2 dual GEMM: out = h@W2s + b2 (f32) ; hn = h@W2n (bf16) ----------
__global__ __launch_bounds__(256) void gemm2_dual_kernel(
    const ushort* __restrict__ hbf, const float* __restrict__ W2s,
    const float* __restrict__ W2n, const float* __restrict__ b2,
    float* __restrict__ out, ushort* __restrict__ hnbf) {
    __shared__ float sW[128 * 128];
    __shared__ float sX[32][128];
    const int tid = threadIdx.x;
    const int rowbase = blockIdx.x * 32;
    for (int idx = tid * 4; idx < 128 * 128; idx += 1024) {
        const int k = idx >> 7, col = idx & 127;
        const float* srcp = (col < 64) ? &W2s[k * 64 + col] : &W2n[k * 64 + (col - 64)];
        *(float4*)&sW[idx] = *(const float4*)srcp;
    }
    for (int idx = tid * 4; idx < 32 * 128; idx += 1024) {
        const int r = rowbase + (idx >> 7);
        const uint2 hv = *(const uint2*)&hbf[(size_t)r * 128 + (idx & 127)];
        const float2 a = unpack_bf2(hv.x);
        const float2 b = unpack_bf2(hv.y);
        float4 f;
        f.x = a.x; f.y = a.y; f.z = b.x; f.w = b.y;
        *(float4*)&sX[0][idx] = f;
    }
    __syncthreads();

    const int c = tid & 31;
    const int c4 = c * 4;
    const int r0 = (tid >> 5) * 4;
    float acc[4][4];
    if (c < 16) {
        const float4 bv = *(const float4*)&b2[c4];
#pragma unroll
        for (int i = 0; i < 4; ++i) {
            acc[i][0] = bv.x; acc[i][1] = bv.y; acc[i][2] = bv.z; acc[i][3] = bv.w;
        }
    } else {
#pragma unroll
        for (int i = 0; i < 4; ++i)
#pragma unroll
            for (int j = 0; j < 4; ++j) acc[i][j] = 0.0f;
    }
#pragma unroll 4
    for (int k = 0; k < 128; ++k) {
        const float4 wv = *(const float4*)&sW[k * 128 + c4];
        const float x0 = sX[r0 + 0][k];
        const float x1 = sX[r0 + 1][k];
        const float x2 = sX[r0 + 2][k];
        const float x3 = sX[r0 + 3][k];
        acc[0][0] = fmaf(x0, wv.x, acc[0][0]); acc[0][1] = fmaf(x0, wv.y, acc[0][1]);
        acc[0][2] = fmaf(x0, wv.z, acc[0][2]); acc[0][3] = fmaf(x0, wv.w, acc[0][3]);
        acc[1][0] = fmaf(x1, wv.x, acc[1][0]); acc[1][1] = fmaf(x1, wv.y, acc[1][1]);
        acc[1][2] = fmaf(x1, wv.z, acc[1][2]); acc[1][3] = fmaf(x1, wv.w, acc[1][3]);
        acc[2][0] = fmaf(x2, wv.x, acc[2][0]); acc[2][1] = fmaf(x2, wv.y, acc[2][1]);
        acc[2][2] = fmaf(x2, wv.z, acc[2][2]); acc[2][3] = fmaf(x2, wv.w, acc[2][3]);
        acc[3][0] = fmaf(x3, wv.x, acc[3][0]); acc[3][1] = fmaf(x3, wv.y, acc[3][1]);
        acc[3][2] = fmaf(x3, wv.z, acc[3][2]); acc[3][3] = fmaf(x3, wv.w, acc[3][3]);
    }
#pragma unroll
    for (int i = 0; i < 4; ++i) {
        const int row = rowbase + r0 + i;
        if (c < 16) {
            float4 o;
            o.x = acc[i][0]; o.y = acc[i][1]; o.z = acc[i][2]; o.w = acc[i][3];
            *(float4*)&out[(size_t)row * 64 + c4] = o;
        } else {
            uint2 o;
            o.x = pack_bf2(acc[i][0], acc[i][1]);
            o.y = pack_bf2(acc[i][2], acc[i][3]);
            *(uint2*)&hnbf[(size_t)row * 64 + (c4 - 64)] = o;
        }
    }
}

// ---------- layer-1 aggregation: h[d] = relu(h[d] + invd[d]*sum(xn[src])) ----------
// one 64-lane wave per node; bf16 gather (uint = 2 cols/lane), f32 accumulate
__global__ __launch_bounds__(256) void agg1_kernel(const int* __restrict__ rs,
                                                   const int* __restrict__ ebuf,
                                                   const float* __restrict__ invd,
                                                   const ushort* __restrict__ xnbf,
                                                   ushort* __restrict__ hbf) {
    const int node = blockIdx.x * 4 + (threadIdx.x >> 6);
    if (node >= NNODES) return;
    const int lane = threadIdx.x & 63;
    const int beg = rs[node];
    const int end = rs[node + 1];
    const uint* fp = (const uint*)xnbf + lane;  // uint index: s*64 + lane
    float ax = 0.0f, ay = 0.0f;
    int i = beg;
    for (; i + 7 < end; i += 8) {
#pragma unroll
        for (int u = 0; u < 8; ++u) {
            const float2 v = unpack_bf2(fp[(size_t)ebuf[i + u] * 64]);
            ax += v.x;
            ay += v.y;
        }
    }
    for (; i < end; ++i) {
        const float2 v = unpack_bf2(fp[(size_t)ebuf[i] * 64]);
        ax += v.x;
        ay += v.y;
    }
    const float w = invd[node];
    uint* hp = (uint*)hbf + (size_t)node * 64 + lane;
    const float2 hv = unpack_bf2(*hp);
    const float rx = fmaxf(fmaf(w, ax, hv.x), 0.0f);
    const float ry = fmaxf(fmaf(w, ay, hv.y), 0.0f);
    *hp = pack_bf2(rx, ry);
}

// ---------- layer-2 aggregation: out[d] += invd[d]*sum(hn[src]) ----------
// one 32-lane group per node; bf16 gather (uint = 2 cols/lane), f32 out RMW
__global__ __launch_bounds__(256) void agg2_kernel(const int* __restrict__ rs,
                                                   const int* __restrict__ ebuf,
                                                   const float* __restrict__ invd,
                                                   const ushort* __restrict__ hnbf,
                                                   float* __restrict__ out) {
    const int node = blockIdx.x * 8 + (threadIdx.x >> 5);
    if (node >= NNODES) return;
    const int lane = threadIdx.x & 31;
    const int beg = rs[node];
    const int end = rs[node + 1];
    const uint* fp = (const uint*)hnbf + lane;  // uint index: s*32 + lane
    float ax = 0.0f, ay = 0.0f;
    int i = beg;
    for (; i + 7 < end; i += 8) {
#pragma unroll
        for (int u = 0; u < 8; ++u) {
            const float2 v = unpack_bf2(fp[(size_t)ebuf[i + u] * 32]);
            ax += v.x;
            ay += v.y;
        }
    }
    for (; i < end; ++i) {
        const float2 v = unpack_bf2(fp[(size_t)ebuf[i] * 32]);
        ax += v.x;
        ay += v.y;
    }
    const float w = invd[node];
    float2* op = (float2*)&out[(size_t)node * 64 + lane * 2];
    float2 ov = *op;
    ov.x = fmaf(w, ax, ov.x);
    ov.y = fmaf(w, ay, ov.y);
    *op = ov;
}

extern "C" void kernel_launch(void* const* d_in, const int* in_sizes, int n_in,
                              void* d_out, int out_size, void* d_ws, size_t ws_size,
                              hipStream_t stream) {
    const float* x   = (const float*)d_in[0];
    const int*   ei  = (const int*)d_in[1];
    const float* W1s = (const float*)d_in[2];
    const float* W1n = (const float*)d_in[3];
    const float* b1  = (const float*)d_in[4];
    const float* W2s = (const float*)d_in[5];
    const float* W2n = (const float*)d_in[6];
    const float* b2  = (const float*)d_in[7];
    float* out = (float*)d_out;

    const int* src = ei;           // edge_index row 0
    const int* dst = ei + NEDGES;  // edge_index row 1

    // workspace carve-up (4B words)
    char* base = (char*)d_ws;
    int*    deg    = (int*)base;                          // 100,096
    float*  invd   = (float*)(base + 100096 * 4);         // 100,096
    int*    rs     = (int*)(base + 200192 * 4);           // 100,352 (N+1)
    int*    cursor = (int*)(base + 300544 * 4);           // 100,096
    int*    bsum   = (int*)(base + 400640 * 4);           // 128
    int*    boffs  = (int*)(base + 400768 * 4);           // 128
    int*    ebuf   = (int*)(base + 400896 * 4);           // 3,200,000
    ushort* xnbf   = (ushort*)(base + 3600896LL * 4);     // N*128 bf16 (6.4M words)
    ushort* hbf    = (ushort*)(base + 10000896LL * 4);    // N*128 bf16 (6.4M words)
    ushort* hnbf   = xnbf;  // reuse: xn dead after agg1 (needs N*64 bf16)

    // ---- CSR build prologue ----
    hipMemsetAsync(deg, 0, NNODES * sizeof(int), stream);
    deg_kernel<<<2048, 256, 0, stream>>>(dst, deg);
    scan_chunk<<<NB_SCAN, 256, 0, stream>>>(deg, rs, bsum);
    scan_bsums<<<1, 128, 0, stream>>>(bsum, boffs);
    finalize_kernel<<<(NNODES + 255) / 256, 256, 0, stream>>>(rs, boffs, cursor, deg, invd);

    // ---- CSR fill co-scheduled with layer-1 GEMMs ----
    mega1_kernel<<<FILLQ * 4, 256, 0, stream>>>(x, W1s, W1n, b1, hbf, xnbf, src, dst,
                                                cursor, ebuf);
    agg1_kernel<<<NNODES / 4, 256, 0, stream>>>(rs, ebuf, invd, xnbf, hbf);

    // ---- layer 2 ----
    gemm2_dual_kernel<<<G1BLOCKS, 256, 0, stream>>>(hbf, W2s, W2n, b2, out, hnbf);
    agg2_kernel<<<NNODES / 8, 256, 0, stream>>>(rs, ebuf, invd, hnbf, out);
}

// Round 5
// 455.906 us; speedup vs baseline: 19.1292x; 1.2690x over previous
//
#include <hip/hip_runtime.h>

#define NNODES 100000
#define NEDGES 3200000
#define NBKT 196        // buckets of 512 nodes (dst>>9)
#define G1BLOCKS 3125   // NNODES/32
#define NTILES 782      // ceil(NEDGES/4096) phase-A tiles

typedef unsigned int uint;
typedef unsigned short ushort;

// ---- bf16 pack/unpack (RNE) ----
__device__ inline uint pack_bf2(float a, float b) {
    uint ua = __float_as_uint(a);
    uint ub = __float_as_uint(b);
    ua = (ua + 0x7FFFu + ((ua >> 16) & 1u)) >> 16;
    ub = (ub + 0x7FFFu + ((ub >> 16) & 1u)) >> 16;
    return ua | (ub << 16);
}
__device__ inline float2 unpack_bf2(uint v) {
    float2 r;
    r.x = __uint_as_float(v << 16);
    r.y = __uint_as_float(v & 0xFFFF0000u);
    return r;
}

// ---------- phase 0: bucket histogram over dst ----------
__global__ __launch_bounds__(256) void hist_kernel(const int* __restrict__ dst,
                                                   int* __restrict__ bhist) {
    __shared__ int lh[NBKT];
    for (int i = threadIdx.x; i < NBKT; i += 256) lh[i] = 0;
    __syncthreads();
    const int n4 = NEDGES / 4;
    for (int i = blockIdx.x * 256 + threadIdx.x; i < n4; i += gridDim.x * 256) {
        const int4 d = ((const int4*)dst)[i];
        atomicAdd(&lh[d.x >> 9], 1);
        atomicAdd(&lh[d.y >> 9], 1);
        atomicAdd(&lh[d.z >> 9], 1);
        atomicAdd(&lh[d.w >> 9], 1);
    }
    __syncthreads();
    for (int i = threadIdx.x; i < NBKT; i += 256)
        if (lh[i]) atomicAdd(&bhist[i], lh[i]);
}

// ---------- scan buckets -> boff, init gcur; rs[N] = E ----------
__global__ __launch_bounds__(256) void scan_bkt(const int* __restrict__ bhist,
                                                int* __restrict__ boff,
                                                int* __restrict__ gcur,
                                                int* __restrict__ rs) {
    __shared__ int s[256];
    const int tid = threadIdx.x;
    const int v = (tid < NBKT) ? bhist[tid] : 0;
    s[tid] = v;
    __syncthreads();
    for (int ofs = 1; ofs < 256; ofs <<= 1) {
        int t = (tid >= ofs) ? s[tid - ofs] : 0;
        __syncthreads();
        s[tid] += t;
        __syncthreads();
    }
    const int excl = s[tid] - v;
    if (tid < NBKT) {
        boff[tid] = excl;
        gcur[tid] = excl;
    }
    if (tid == NBKT - 1) {
        boff[NBKT] = s[tid];
        rs[NNODES] = NEDGES;
    }
}

// ---------- megaA: layer-1 dual GEMM (8/9 blocks) + phase-A edge binning (1/9) ----
__global__ __launch_bounds__(256) void megaA_kernel(
    const float* __restrict__ x, const float* __restrict__ W1s,
    const float* __restrict__ W1n, const float* __restrict__ b1,
    ushort* __restrict__ hbf, ushort* __restrict__ xnbf,
    const int* __restrict__ src, const int* __restrict__ dst,
    int* __restrict__ gcur, int2* __restrict__ pairbuf) {
    __shared__ int smem[20480];  // 80 KB
    const int bid = blockIdx.x;
    const int tid = threadIdx.x;

    if ((bid % 9) == 8) {
        // ---------- phase A: tile-sort 4096 edges by bucket ----------
        int* tsrc = smem;                    // 4096
        int* tdst = smem + 4096;             // 4096
        int2* spair = (int2*)(smem + 8192);  // 4096 int2 (8192 words)
        int* lhist = smem + 16384;           // 256
        int* lofs = smem + 16640;            // 256
        int* gbl = smem + 16896;             // 256
        int* lcur = smem + 17152;            // 256
        const int t = bid / 9;
        if (t >= NTILES) return;
        const int ebase = t * 4096;
        const int n = min(4096, NEDGES - ebase);
        for (int i = tid; i < (n >> 2); i += 256) {
            ((int4*)tsrc)[i] = ((const int4*)(src + ebase))[i];
            ((int4*)tdst)[i] = ((const int4*)(dst + ebase))[i];
        }
        lhist[tid] = 0;
        lcur[tid] = 0;
        __syncthreads();
        for (int i = tid; i < n; i += 256) atomicAdd(&lhist[tdst[i] >> 9], 1);
        __syncthreads();
        const int v = lhist[tid];
        lofs[tid] = v;
        __syncthreads();
        for (int ofs = 1; ofs < 256; ofs <<= 1) {
            int tv = (tid >= ofs) ? lofs[tid - ofs] : 0;
            __syncthreads();
            lofs[tid] += tv;
            __syncthreads();
        }
        const int excl = lofs[tid] - v;
        lofs[tid] = excl;
        if (tid < NBKT && v > 0) gbl[tid] = atomicAdd(&gcur[tid], v);
        __syncthreads();
        for (int i = tid; i < n; i += 256) {
            const int s_ = tsrc[i];
            const int d_ = tdst[i];
            const int b = d_ >> 9;
            const int p = atomicAdd(&lcur[b], 1) + lofs[b];
            spair[p] = make_int2(s_, d_);
        }
        __syncthreads();
        for (int p = tid; p < n; p += 256) {
            const int2 e = spair[p];
            const int b = e.y >> 9;
            pairbuf[gbl[b] + (p - lofs[b])] = e;
        }
        return;
    }

    // ---------- GEMM branch ----------
    float* sW = (float*)smem;           // 128*128
    float* sX = (float*)(smem + 16384); // 32*128
    const int g = (bid / 9) * 8 + (bid % 9);
    if (g >= 2 * G1BLOCKS) return;
    const bool self = g < G1BLOCKS;
    const float* __restrict__ W = self ? W1s : W1n;
    ushort* __restrict__ Y = self ? hbf : xnbf;
    const int rowbase = (self ? g : g - G1BLOCKS) * 32;

    for (int idx = tid * 4; idx < 128 * 128; idx += 1024)
        *(float4*)&sW[idx] = *(const float4*)&W[idx];
    for (int idx = tid * 4; idx < 32 * 128; idx += 1024) {
        const int r = rowbase + (idx >> 7);
        *(float4*)&sX[idx] = *(const float4*)&x[(size_t)r * 128 + (idx & 127)];
    }
    __syncthreads();

    const int c4 = (tid & 31) * 4;
    const int r0 = (tid >> 5) * 4;
    float acc[4][4];
    if (self) {
        const float4 bv = *(const float4*)&b1[c4];
#pragma unroll
        for (int i = 0; i < 4; ++i) {
            acc[i][0] = bv.x; acc[i][1] = bv.y; acc[i][2] = bv.z; acc[i][3] = bv.w;
        }
    } else {
#pragma unroll
        for (int i = 0; i < 4; ++i)
#pragma unroll
            for (int j = 0; j < 4; ++j) acc[i][j] = 0.0f;
    }
#pragma unroll 4
    for (int k = 0; k < 128; ++k) {
        const float4 wv = *(const float4*)&sW[k * 128 + c4];
        const float x0 = sX[(r0 + 0) * 128 + k];
        const float x1 = sX[(r0 + 1) * 128 + k];
        const float x2 = sX[(r0 + 2) * 128 + k];
        const float x3 = sX[(r0 + 3) * 128 + k];
        acc[0][0] = fmaf(x0, wv.x, acc[0][0]); acc[0][1] = fmaf(x0, wv.y, acc[0][1]);
        acc[0][2] = fmaf(x0, wv.z, acc[0][2]); acc[0][3] = fmaf(x0, wv.w, acc[0][3]);
        acc[1][0] = fmaf(x1, wv.x, acc[1][0]); acc[1][1] = fmaf(x1, wv.y, acc[1][1]);
        acc[1][2] = fmaf(x1, wv.z, acc[1][2]); acc[1][3] = fmaf(x1, wv.w, acc[1][3]);
        acc[2][0] = fmaf(x2, wv.x, acc[2][0]); acc[2][1] = fmaf(x2, wv.y, acc[2][1]);
        acc[2][2] = fmaf(x2, wv.z, acc[2][2]); acc[2][3] = fmaf(x2, wv.w, acc[2][3]);
        acc[3][0] = fmaf(x3, wv.x, acc[3][0]); acc[3][1] = fmaf(x3, wv.y, acc[3][1]);
        acc[3][2] = fmaf(x3, wv.z, acc[3][2]); acc[3][3] = fmaf(x3, wv.w, acc[3][3]);
    }
#pragma unroll
    for (int i = 0; i < 4; ++i) {
        uint2 o;
        o.x = pack_bf2(acc[i][0], acc[i][1]);
        o.y = pack_bf2(acc[i][2], acc[i][3]);
        *(uint2*)&Y[(size_t)(rowbase + r0 + i) * 128 + c4] = o;
    }
}

// ---------- phase B: per-bucket CSR finalize (deg/invd/rs/ebuf) ----------
__global__ __launch_bounds__(256) void bucket_kernel(const int2* __restrict__ pairbuf,
                                                     const int* __restrict__ boff,
                                                     int* __restrict__ rs,
                                                     float* __restrict__ invd,
                                                     int* __restrict__ ebuf) {
    __shared__ int ndeg[512];
    __shared__ int nofs[512];
    __shared__ int lcur[512];
    __shared__ int sps[256];
    const int b = blockIdx.x;
    const int tid = threadIdx.x;
    const int nb = b << 9;
    const int ln = min(512, NNODES - nb);
    const int base = boff[b];
    const int cnt = boff[b + 1] - base;
    for (int i = tid; i < 512; i += 256) {
        ndeg[i] = 0;
        lcur[i] = 0;
    }
    __syncthreads();
    for (int i = tid; i < cnt; i += 256) {
        const int2 e = pairbuf[base + i];
        atomicAdd(&ndeg[e.y - nb], 1);
    }
    __syncthreads();
    for (int nidx = tid; nidx < ln; nidx += 256)
        invd[nb + nidx] = 1.0f / fmaxf((float)ndeg[nidx], 1.0f);
    // exclusive scan of ndeg[0..512) (2 elems/thread)
    const int a0 = ndeg[2 * tid];
    const int a1 = ndeg[2 * tid + 1];
    sps[tid] = a0 + a1;
    __syncthreads();
    for (int ofs = 1; ofs < 256; ofs <<= 1) {
        int t = (tid >= ofs) ? sps[tid - ofs] : 0;
        __syncthreads();
        sps[tid] += t;
        __syncthreads();
    }
    const int excl = sps[tid] - (a0 + a1);
    nofs[2 * tid] = excl;
    nofs[2 * tid + 1] = excl + a0;
    __syncthreads();
    for (int nidx = tid; nidx < ln; nidx += 256) rs[nb + nidx] = base + nofs[nidx];
    for (int i = tid; i < cnt; i += 256) {
        const int2 e = pairbuf[base + i];
        const int nn = e.y - nb;
        const int p = atomicAdd(&lcur[nn], 1);
        ebuf[base + nofs[nn] + p] = e.x;  // 4B random within 64KB single-block region
    }
}

// ---------- layer-2 dual GEMM: out = h@W2s + b2 (f32) ; hn = h@W2n (bf16) ----------
__global__ __launch_bounds__(256) void gemm2_dual_kernel(
    const ushort* __restrict__ hbf, const float* __restrict__ W2s,
    const float* __restrict__ W2n, const float* __restrict__ b2,
    float* __restrict__ out, ushort* __restrict__ hnbf) {
    __shared__ float sW[128 * 128];
    __shared__ float sX[32][128];
    const int tid = threadIdx.x;
    const int rowbase = blockIdx.x * 32;
    for (int idx = tid * 4; idx < 128 * 128; idx += 1024) {
        const int k = idx >> 7, col = idx & 127;
        const float* srcp = (col < 64) ? &W2s[k * 64 + col] : &W2n[k * 64 + (col - 64)];
        *(float4*)&sW[idx] = *(const float4*)srcp;
    }
    for (int idx = tid * 4; idx < 32 * 128; idx += 1024) {
        const int r = rowbase + (idx >> 7);
        const uint2 hv = *(const uint2*)&hbf[(size_t)r * 128 + (idx & 127)];
        const float2 a = unpack_bf2(hv.x);
        const float2 b = unpack_bf2(hv.y);
        float4 f;
        f.x = a.x; f.y = a.y; f.z = b.x; f.w = b.y;
        *(float4*)&sX[0][idx] = f;
    }
    __syncthreads();

    const int c = tid & 31;
    const int c4 = c * 4;
    const int r0 = (tid >> 5) * 4;
    float acc[4][4];
    if (c < 16) {
        const float4 bv = *(const float4*)&b2[c4];
#pragma unroll
        for (int i = 0; i < 4; ++i) {
            acc[i][0] = bv.x; acc[i][1] = bv.y; acc[i][2] = bv.z; acc[i][3] = bv.w;
        }
    } else {
#pragma unroll
        for (int i = 0; i < 4; ++i)
#pragma unroll
            for (int j = 0; j < 4; ++j) acc[i][j] = 0.0f;
    }
#pragma unroll 4
    for (int k = 0; k < 128; ++k) {
        const float4 wv = *(const float4*)&sW[k * 128 + c4];
        const float x0 = sX[r0 + 0][k];
        const float x1 = sX[r0 + 1][k];
        const float x2 = sX[r0 + 2][k];
        const float x3 = sX[r0 + 3][k];
        acc[0][0] = fmaf(x0, wv.x, acc[0][0]); acc[0][1] = fmaf(x0, wv.y, acc[0][1]);
        acc[0][2] = fmaf(x0, wv.z, acc[0][2]); acc[0][3] = fmaf(x0, wv.w, acc[0][3]);
        acc[1][0] = fmaf(x1, wv.x, acc[1][0]); acc[1][1] = fmaf(x1, wv.y, acc[1][1]);
        acc[1][2] = fmaf(x1, wv.z, acc[1][2]); acc[1][3] = fmaf(x1, wv.w, acc[1][3]);
        acc[2][0] = fmaf(x2, wv.x, acc[2][0]); acc[2][1] = fmaf(x2, wv.y, acc[2][1]);
        acc[2][2] = fmaf(x2, wv.z, acc[2][2]); acc[2][3] = fmaf(x2, wv.w, acc[2][3]);
        acc[3][0] = fmaf(x3, wv.x, acc[3][0]); acc[3][1] = fmaf(x3, wv.y, acc[3][1]);
        acc[3][2] = fmaf(x3, wv.z, acc[3][2]); acc[3][3] = fmaf(x3, wv.w, acc[3][3]);
    }
#pragma unroll
    for (int i = 0; i < 4; ++i) {
        const int row = rowbase + r0 + i;
        if (c < 16) {
            float4 o;
            o.x = acc[i][0]; o.y = acc[i][1]; o.z = acc[i][2]; o.w = acc[i][3];
            *(float4*)&out[(size_t)row * 64 + c4] = o;
        } else {
            uint2 o;
            o.x = pack_bf2(acc[i][0], acc[i][1]);
            o.y = pack_bf2(acc[i][2], acc[i][3]);
            *(uint2*)&hnbf[(size_t)row * 64 + (c4 - 64)] = o;
        }
    }
}

// ---------- layer-1 aggregation ----------
__global__ __launch_bounds__(256) void agg1_kernel(const int* __restrict__ rs,
                                                   const int* __restrict__ ebuf,
                                                   const float* __restrict__ invd,
                                                   const ushort* __restrict__ xnbf,
                                                   ushort* __restrict__ hbf) {
    const int node = blockIdx.x * 4 + (threadIdx.x >> 6);
    if (node >= NNODES) return;
    const int lane = threadIdx.x & 63;
    const int beg = rs[node];
    const int end = rs[node + 1];
    const uint* fp = (const uint*)xnbf + lane;
    float ax = 0.0f, ay = 0.0f;
    int i = beg;
    for (; i + 7 < end; i += 8) {
#pragma unroll
        for (int u = 0; u < 8; ++u) {
            const float2 v = unpack_bf2(fp[(size_t)ebuf[i + u] * 64]);
            ax += v.x;
            ay += v.y;
        }
    }
    for (; i < end; ++i) {
        const float2 v = unpack_bf2(fp[(size_t)ebuf[i] * 64]);
        ax += v.x;
        ay += v.y;
    }
    const float w = invd[node];
    uint* hp = (uint*)hbf + (size_t)node * 64 + lane;
    const float2 hv = unpack_bf2(*hp);
    const float rx = fmaxf(fmaf(w, ax, hv.x), 0.0f);
    const float ry = fmaxf(fmaf(w, ay, hv.y), 0.0f);
    *hp = pack_bf2(rx, ry);
}

// ---------- layer-2 aggregation ----------
__global__ __launch_bounds__(256) void agg2_kernel(const int* __restrict__ rs,
                                                   const int* __restrict__ ebuf,
                                                   const float* __restrict__ invd,
                                                   const ushort* __restrict__ hnbf,
                                                   float* __restrict__ out) {
    const int node = blockIdx.x * 8 + (threadIdx.x >> 5);
    if (node >= NNODES) return;
    const int lane = threadIdx.x & 31;
    const int beg = rs[node];
    const int end = rs[node + 1];
    const uint* fp = (const uint*)hnbf + lane;
    float ax = 0.0f, ay = 0.0f;
    int i = beg;
    for (; i + 7 < end; i += 8) {
#pragma unroll
        for (int u = 0; u < 8; ++u) {
            const float2 v = unpack_bf2(fp[(size_t)ebuf[i + u] * 32]);
            ax += v.x;
            ay += v.y;
        }
    }
    for (; i < end; ++i) {
        const float2 v = unpack_bf2(fp[(size_t)ebuf[i] * 32]);
        ax += v.x;
        ay += v.y;
    }
    const float w = invd[node];
    float2* op = (float2*)&out[(size_t)node * 64 + lane * 2];
    float2 ov = *op;
    ov.x = fmaf(w, ax, ov.x);
    ov.y = fmaf(w, ay, ov.y);
    *op = ov;
}

extern "C" void kernel_launch(void* const* d_in, const int* in_sizes, int n_in,
                              void* d_out, int out_size, void* d_ws, size_t ws_size,
                              hipStream_t stream) {
    const float* x   = (const float*)d_in[0];
    const int*   ei  = (const int*)d_in[1];
    const float* W1s = (const float*)d_in[2];
    const float* W1n = (const float*)d_in[3];
    const float* b1  = (const float*)d_in[4];
    const float* W2s = (const float*)d_in[5];
    const float* W2n = (const float*)d_in[6];
    const float* b2  = (const float*)d_in[7];
    float* out = (float*)d_out;

    const int* src = ei;           // edge_index row 0
    const int* dst = ei + NEDGES;  // edge_index row 1

    // workspace carve-up (word offsets)
    int* w = (int*)d_ws;
    int*    bhist   = w;                        // 256
    int*    boff    = w + 256;                  // 256 (need 197)
    int*    gcur    = w + 512;                  // 256
    int*    rs      = w + 768;                  // 100,001 -> pad 100,864
    float*  invd    = (float*)(w + 100864);     // 100,000
    int*    ebuf    = w + 200864;               // 3,200,000
    int2*   pairbuf = (int2*)(w + 3400864);     // 3,200,000 int2 (6.4M words)
    ushort* xnbf    = (ushort*)(w + 9800864);   // N*128 bf16 (6.4M words)
    ushort* hbf     = (ushort*)(w + 16200864);  // N*128 bf16 (6.4M words)
    ushort* hnbf    = xnbf;  // reuse after agg1

    hipMemsetAsync(bhist, 0, 256 * sizeof(int), stream);
    hist_kernel<<<512, 256, 0, stream>>>(dst, bhist);
    scan_bkt<<<1, 256, 0, stream>>>(bhist, boff, gcur, rs);

    // layer-1 dual GEMM fused with phase-A edge binning
    megaA_kernel<<<NTILES * 9, 256, 0, stream>>>(x, W1s, W1n, b1, hbf, xnbf, src, dst,
                                                 gcur, pairbuf);
    bucket_kernel<<<NBKT, 256, 0, stream>>>(pairbuf, boff, rs, invd, ebuf);

    agg1_kernel<<<NNODES / 4, 256, 0, stream>>>(rs, ebuf, invd, xnbf, hbf);

    gemm2_dual_kernel<<<G1BLOCKS, 256, 0, stream>>>(hbf, W2s, W2n, b2, out, hnbf);
    agg2_kernel<<<NNODES / 8, 256, 0, stream>>>(rs, ebuf, invd, hnbf, out);
}

// Round 6
// 428.636 us; speedup vs baseline: 20.3463x; 1.0636x over previous
//
#include <hip/hip_runtime.h>

#define NNODES 100000
#define NEDGES 3200000
#define NBKT 196        // buckets of 512 nodes (dst>>9)
#define G1BLOCKS 3125   // NNODES/32
#define NTILES 782      // ceil(NEDGES/4096) phase-A tiles

typedef unsigned int uint;
typedef unsigned short ushort;

// ---- bf16 pack/unpack (RNE) ----
__device__ inline uint pack_bf2(float a, float b) {
    uint ua = __float_as_uint(a);
    uint ub = __float_as_uint(b);
    ua = (ua + 0x7FFFu + ((ua >> 16) & 1u)) >> 16;
    ub = (ub + 0x7FFFu + ((ub >> 16) & 1u)) >> 16;
    return ua | (ub << 16);
}
__device__ inline float2 unpack_bf2(uint v) {
    float2 r;
    r.x = __uint_as_float(v << 16);
    r.y = __uint_as_float(v & 0xFFFF0000u);
    return r;
}

// ---------- phase 0: bucket histogram over dst ----------
__global__ __launch_bounds__(256) void hist_kernel(const int* __restrict__ dst,
                                                   int* __restrict__ bhist) {
    __shared__ int lh[NBKT];
    for (int i = threadIdx.x; i < NBKT; i += 256) lh[i] = 0;
    __syncthreads();
    const int n4 = NEDGES / 4;
    for (int i = blockIdx.x * 256 + threadIdx.x; i < n4; i += gridDim.x * 256) {
        const int4 d = ((const int4*)dst)[i];
        atomicAdd(&lh[d.x >> 9], 1);
        atomicAdd(&lh[d.y >> 9], 1);
        atomicAdd(&lh[d.z >> 9], 1);
        atomicAdd(&lh[d.w >> 9], 1);
    }
    __syncthreads();
    for (int i = threadIdx.x; i < NBKT; i += 256)
        if (lh[i]) atomicAdd(&bhist[i], lh[i]);
}

// ---------- scan buckets -> boff, init gcur; rs[N] = E ----------
__global__ __launch_bounds__(256) void scan_bkt(const int* __restrict__ bhist,
                                                int* __restrict__ boff,
                                                int* __restrict__ gcur,
                                                int* __restrict__ rs) {
    __shared__ int s[256];
    const int tid = threadIdx.x;
    const int v = (tid < NBKT) ? bhist[tid] : 0;
    s[tid] = v;
    __syncthreads();
    for (int ofs = 1; ofs < 256; ofs <<= 1) {
        int t = (tid >= ofs) ? s[tid - ofs] : 0;
        __syncthreads();
        s[tid] += t;
        __syncthreads();
    }
    const int excl = s[tid] - v;
    if (tid < NBKT) {
        boff[tid] = excl;
        gcur[tid] = excl;
    }
    if (tid == NBKT - 1) {
        boff[NBKT] = s[tid];
        rs[NNODES] = NEDGES;
    }
}

// ---------- megaA: layer-1 dual GEMM (8/9 blocks) + phase-A edge binning (1/9) ----
__global__ __launch_bounds__(256) void megaA_kernel(
    const float* __restrict__ x, const float* __restrict__ W1s,
    const float* __restrict__ W1n, const float* __restrict__ b1,
    ushort* __restrict__ hbf, ushort* __restrict__ xnbf,
    const int* __restrict__ src, const int* __restrict__ dst,
    int* __restrict__ gcur, int2* __restrict__ pairbuf) {
    __shared__ int smem[20480];  // 80 KB
    const int bid = blockIdx.x;
    const int tid = threadIdx.x;

    if ((bid % 9) == 8) {
        // ---------- phase A: tile-sort 4096 edges by bucket ----------
        int* tsrc = smem;                    // 4096
        int* tdst = smem + 4096;             // 4096
        int2* spair = (int2*)(smem + 8192);  // 4096 int2 (8192 words)
        int* lhist = smem + 16384;           // 256
        int* lofs = smem + 16640;            // 256
        int* gbl = smem + 16896;             // 256
        int* lcur = smem + 17152;            // 256
        const int t = bid / 9;
        if (t >= NTILES) return;
        const int ebase = t * 4096;
        const int n = min(4096, NEDGES - ebase);
        for (int i = tid; i < (n >> 2); i += 256) {
            ((int4*)tsrc)[i] = ((const int4*)(src + ebase))[i];
            ((int4*)tdst)[i] = ((const int4*)(dst + ebase))[i];
        }
        lhist[tid] = 0;
        lcur[tid] = 0;
        __syncthreads();
        for (int i = tid; i < n; i += 256) atomicAdd(&lhist[tdst[i] >> 9], 1);
        __syncthreads();
        const int v = lhist[tid];
        lofs[tid] = v;
        __syncthreads();
        for (int ofs = 1; ofs < 256; ofs <<= 1) {
            int tv = (tid >= ofs) ? lofs[tid - ofs] : 0;
            __syncthreads();
            lofs[tid] += tv;
            __syncthreads();
        }
        const int excl = lofs[tid] - v;
        lofs[tid] = excl;
        if (tid < NBKT && v > 0) gbl[tid] = atomicAdd(&gcur[tid], v);
        __syncthreads();
        for (int i = tid; i < n; i += 256) {
            const int s_ = tsrc[i];
            const int d_ = tdst[i];
            const int b = d_ >> 9;
            const int p = atomicAdd(&lcur[b], 1) + lofs[b];
            spair[p] = make_int2(s_, d_);
        }
        __syncthreads();
        for (int p = tid; p < n; p += 256) {
            const int2 e = spair[p];
            const int b = e.y >> 9;
            pairbuf[gbl[b] + (p - lofs[b])] = e;
        }
        return;
    }

    // ---------- GEMM branch (transposed X tile: sXT[k][r], stride 32) ----------
    float* sW = (float*)smem;            // 128*128
    float* sXT = (float*)(smem + 16384); // 128*32
    const int g = (bid / 9) * 8 + (bid % 9);
    if (g >= 2 * G1BLOCKS) return;
    const bool self = g < G1BLOCKS;
    const float* __restrict__ W = self ? W1s : W1n;
    ushort* __restrict__ Y = self ? hbf : xnbf;
    const int rowbase = (self ? g : g - G1BLOCKS) * 32;

    for (int idx = tid * 4; idx < 128 * 128; idx += 1024)
        *(float4*)&sW[idx] = *(const float4*)&W[idx];
    {
        const int r = tid & 31;          // local row
        const int k0 = (tid >> 5) * 4;   // k offset within 32-chunk
#pragma unroll
        for (int kk = 0; kk < 128; kk += 32) {
            const float4 v =
                *(const float4*)&x[(size_t)(rowbase + r) * 128 + kk + k0];
            sXT[(kk + k0 + 0) * 32 + r] = v.x;
            sXT[(kk + k0 + 1) * 32 + r] = v.y;
            sXT[(kk + k0 + 2) * 32 + r] = v.z;
            sXT[(kk + k0 + 3) * 32 + r] = v.w;
        }
    }
    __syncthreads();

    const int c4 = (tid & 31) * 4;
    const int r0 = (tid >> 5) * 4;
    float acc[4][4];
    if (self) {
        const float4 bv = *(const float4*)&b1[c4];
#pragma unroll
        for (int i = 0; i < 4; ++i) {
            acc[i][0] = bv.x; acc[i][1] = bv.y; acc[i][2] = bv.z; acc[i][3] = bv.w;
        }
    } else {
#pragma unroll
        for (int i = 0; i < 4; ++i)
#pragma unroll
            for (int j = 0; j < 4; ++j) acc[i][j] = 0.0f;
    }
#pragma unroll 8
    for (int k = 0; k < 128; ++k) {
        const float4 wv = *(const float4*)&sW[k * 128 + c4];
        const float4 xv = *(const float4*)&sXT[k * 32 + r0];
        acc[0][0] = fmaf(xv.x, wv.x, acc[0][0]); acc[0][1] = fmaf(xv.x, wv.y, acc[0][1]);
        acc[0][2] = fmaf(xv.x, wv.z, acc[0][2]); acc[0][3] = fmaf(xv.x, wv.w, acc[0][3]);
        acc[1][0] = fmaf(xv.y, wv.x, acc[1][0]); acc[1][1] = fmaf(xv.y, wv.y, acc[1][1]);
        acc[1][2] = fmaf(xv.y, wv.z, acc[1][2]); acc[1][3] = fmaf(xv.y, wv.w, acc[1][3]);
        acc[2][0] = fmaf(xv.z, wv.x, acc[2][0]); acc[2][1] = fmaf(xv.z, wv.y, acc[2][1]);
        acc[2][2] = fmaf(xv.z, wv.z, acc[2][2]); acc[2][3] = fmaf(xv.z, wv.w, acc[2][3]);
        acc[3][0] = fmaf(xv.w, wv.x, acc[3][0]); acc[3][1] = fmaf(xv.w, wv.y, acc[3][1]);
        acc[3][2] = fmaf(xv.w, wv.z, acc[3][2]); acc[3][3] = fmaf(xv.w, wv.w, acc[3][3]);
    }
#pragma unroll
    for (int i = 0; i < 4; ++i) {
        uint2 o;
        o.x = pack_bf2(acc[i][0], acc[i][1]);
        o.y = pack_bf2(acc[i][2], acc[i][3]);
        *(uint2*)&Y[(size_t)(rowbase + r0 + i) * 128 + c4] = o;
    }
}

// ---------- phase B: per-bucket CSR finalize (deg/invd/rs/ebuf) ----------
__global__ __launch_bounds__(256) void bucket_kernel(const int2* __restrict__ pairbuf,
                                                     const int* __restrict__ boff,
                                                     int* __restrict__ rs,
                                                     float* __restrict__ invd,
                                                     int* __restrict__ ebuf) {
    __shared__ int ndeg[512];
    __shared__ int nofs[512];
    __shared__ int lcur[512];
    __shared__ int sps[256];
    const int b = blockIdx.x;
    const int tid = threadIdx.x;
    const int nb = b << 9;
    const int ln = min(512, NNODES - nb);
    const int base = boff[b];
    const int cnt = boff[b + 1] - base;
    for (int i = tid; i < 512; i += 256) {
        ndeg[i] = 0;
        lcur[i] = 0;
    }
    __syncthreads();
    for (int i = tid; i < cnt; i += 256) {
        const int2 e = pairbuf[base + i];
        atomicAdd(&ndeg[e.y - nb], 1);
    }
    __syncthreads();
    for (int nidx = tid; nidx < ln; nidx += 256)
        invd[nb + nidx] = 1.0f / fmaxf((float)ndeg[nidx], 1.0f);
    // exclusive scan of ndeg[0..512) (2 elems/thread)
    const int a0 = ndeg[2 * tid];
    const int a1 = ndeg[2 * tid + 1];
    sps[tid] = a0 + a1;
    __syncthreads();
    for (int ofs = 1; ofs < 256; ofs <<= 1) {
        int t = (tid >= ofs) ? sps[tid - ofs] : 0;
        __syncthreads();
        sps[tid] += t;
        __syncthreads();
    }
    const int excl = sps[tid] - (a0 + a1);
    nofs[2 * tid] = excl;
    nofs[2 * tid + 1] = excl + a0;
    __syncthreads();
    for (int nidx = tid; nidx < ln; nidx += 256) rs[nb + nidx] = base + nofs[nidx];
    for (int i = tid; i < cnt; i += 256) {
        const int2 e = pairbuf[base + i];
        const int nn = e.y - nb;
        const int p = atomicAdd(&lcur[nn], 1);
        ebuf[base + nofs[nn] + p] = e.x;
    }
}

// ---------- layer-2 dual GEMM: out = h@W2s + b2 (f32) ; hn = h@W2n (bf16) ----------
__global__ __launch_bounds__(256) void gemm2_dual_kernel(
    const ushort* __restrict__ hbf, const float* __restrict__ W2s,
    const float* __restrict__ W2n, const float* __restrict__ b2,
    float* __restrict__ out, ushort* __restrict__ hnbf) {
    __shared__ float sW[128 * 128];
    __shared__ float sXT[128 * 32];
    const int tid = threadIdx.x;
    const int rowbase = blockIdx.x * 32;
    for (int idx = tid * 4; idx < 128 * 128; idx += 1024) {
        const int k = idx >> 7, col = idx & 127;
        const float* srcp = (col < 64) ? &W2s[k * 64 + col] : &W2n[k * 64 + (col - 64)];
        *(float4*)&sW[idx] = *(const float4*)srcp;
    }
    {
        const int r = tid & 31;
        const int k0 = (tid >> 5) * 4;
#pragma unroll
        for (int kk = 0; kk < 128; kk += 32) {
            const uint2 hv =
                *(const uint2*)&hbf[(size_t)(rowbase + r) * 128 + kk + k0];
            const float2 a = unpack_bf2(hv.x);
            const float2 b = unpack_bf2(hv.y);
            sXT[(kk + k0 + 0) * 32 + r] = a.x;
            sXT[(kk + k0 + 1) * 32 + r] = a.y;
            sXT[(kk + k0 + 2) * 32 + r] = b.x;
            sXT[(kk + k0 + 3) * 32 + r] = b.y;
        }
    }
    __syncthreads();

    const int c = tid & 31;
    const int c4 = c * 4;
    const int r0 = (tid >> 5) * 4;
    float acc[4][4];
    if (c < 16) {
        const float4 bv = *(const float4*)&b2[c4];
#pragma unroll
        for (int i = 0; i < 4; ++i) {
            acc[i][0] = bv.x; acc[i][1] = bv.y; acc[i][2] = bv.z; acc[i][3] = bv.w;
        }
    } else {
#pragma unroll
        for (int i = 0; i < 4; ++i)
#pragma unroll
            for (int j = 0; j < 4; ++j) acc[i][j] = 0.0f;
    }
#pragma unroll 8
    for (int k = 0; k < 128; ++k) {
        const float4 wv = *(const float4*)&sW[k * 128 + c4];
        const float4 xv = *(const float4*)&sXT[k * 32 + r0];
        acc[0][0] = fmaf(xv.x, wv.x, acc[0][0]); acc[0][1] = fmaf(xv.x, wv.y, acc[0][1]);
        acc[0][2] = fmaf(xv.x, wv.z, acc[0][2]); acc[0][3] = fmaf(xv.x, wv.w, acc[0][3]);
        acc[1][0] = fmaf(xv.y, wv.x, acc[1][0]); acc[1][1] = fmaf(xv.y, wv.y, acc[1][1]);
        acc[1][2] = fmaf(xv.y, wv.z, acc[1][2]); acc[1][3] = fmaf(xv.y, wv.w, acc[1][3]);
        acc[2][0] = fmaf(xv.z, wv.x, acc[2][0]); acc[2][1] = fmaf(xv.z, wv.y, acc[2][1]);
        acc[2][2] = fmaf(xv.z, wv.z, acc[2][2]); acc[2][3] = fmaf(xv.z, wv.w, acc[2][3]);
        acc[3][0] = fmaf(xv.w, wv.x, acc[3][0]); acc[3][1] = fmaf(xv.w, wv.y, acc[3][1]);
        acc[3][2] = fmaf(xv.w, wv.z, acc[3][2]); acc[3][3] = fmaf(xv.w, wv.w, acc[3][3]);
    }
#pragma unroll
    for (int i = 0; i < 4; ++i) {
        const int row = rowbase + r0 + i;
        if (c < 16) {
            float4 o;
            o.x = acc[i][0]; o.y = acc[i][1]; o.z = acc[i][2]; o.w = acc[i][3];
            *(float4*)&out[(size_t)row * 64 + c4] = o;
        } else {
            uint2 o;
            o.x = pack_bf2(acc[i][0], acc[i][1]);
            o.y = pack_bf2(acc[i][2], acc[i][3]);
            *(uint2*)&hnbf[(size_t)row * 64 + (c4 - 64)] = o;
        }
    }
}

// ---------- layer-1 aggregation ----------
__global__ __launch_bounds__(256) void agg1_kernel(const int* __restrict__ rs,
                                                   const int* __restrict__ ebuf,
                                                   const float* __restrict__ invd,
                                                   const ushort* __restrict__ xnbf,
                                                   ushort* __restrict__ hbf) {
    const int node = blockIdx.x * 4 + (threadIdx.x >> 6);
    if (node >= NNODES) return;
    const int lane = threadIdx.x & 63;
    const int beg = rs[node];
    const int end = rs[node + 1];
    const uint* fp = (const uint*)xnbf + lane;
    float ax = 0.0f, ay = 0.0f;
    int i = beg;
    for (; i + 7 < end; i += 8) {
#pragma unroll
        for (int u = 0; u < 8; ++u) {
            const float2 v = unpack_bf2(fp[(size_t)ebuf[i + u] * 64]);
            ax += v.x;
            ay += v.y;
        }
    }
    for (; i < end; ++i) {
        const float2 v = unpack_bf2(fp[(size_t)ebuf[i] * 64]);
        ax += v.x;
        ay += v.y;
    }
    const float w = invd[node];
    uint* hp = (uint*)hbf + (size_t)node * 64 + lane;
    const float2 hv = unpack_bf2(*hp);
    const float rx = fmaxf(fmaf(w, ax, hv.x), 0.0f);
    const float ry = fmaxf(fmaf(w, ay, hv.y), 0.0f);
    *hp = pack_bf2(rx, ry);
}

// ---------- layer-2 aggregation ----------
__global__ __launch_bounds__(256) void agg2_kernel(const int* __restrict__ rs,
                                                   const int* __restrict__ ebuf,
                                                   const float* __restrict__ invd,
                                                   const ushort* __restrict__ hnbf,
                                                   float* __restrict__ out) {
    const int node = blockIdx.x * 8 + (threadIdx.x >> 5);
    if (node >= NNODES) return;
    const int lane = threadIdx.x & 31;
    const int beg = rs[node];
    const int end = rs[node + 1];
    const uint* fp = (const uint*)hnbf + lane;
    float ax = 0.0f, ay = 0.0f;
    int i = beg;
    for (; i + 7 < end; i += 8) {
#pragma unroll
        for (int u = 0; u < 8; ++u) {
            const float2 v = unpack_bf2(fp[(size_t)ebuf[i + u] * 32]);
            ax += v.x;
            ay += v.y;
        }
    }
    for (; i < end; ++i) {
        const float2 v = unpack_bf2(fp[(size_t)ebuf[i] * 32]);
        ax += v.x;
        ay += v.y;
    }
    const float w = invd[node];
    float2* op = (float2*)&out[(size_t)node * 64 + lane * 2];
    float2 ov = *op;
    ov.x = fmaf(w, ax, ov.x);
    ov.y = fmaf(w, ay, ov.y);
    *op = ov;
}

extern "C" void kernel_launch(void* const* d_in, const int* in_sizes, int n_in,
                              void* d_out, int out_size, void* d_ws, size_t ws_size,
                              hipStream_t stream) {
    const float* x   = (const float*)d_in[0];
    const int*   ei  = (const int*)d_in[1];
    const float* W1s = (const float*)d_in[2];
    const float* W1n = (const float*)d_in[3];
    const float* b1  = (const float*)d_in[4];
    const float* W2s = (const float*)d_in[5];
    const float* W2n = (const float*)d_in[6];
    const float* b2  = (const float*)d_in[7];
    float* out = (float*)d_out;

    const int* src = ei;           // edge_index row 0
    const int* dst = ei + NEDGES;  // edge_index row 1

    // workspace carve-up (word offsets)
    int* w = (int*)d_ws;
    int*    bhist   = w;                        // 256
    int*    boff    = w + 256;                  // 256 (need 197)
    int*    gcur    = w + 512;                  // 256
    int*    rs      = w + 768;                  // 100,001 -> pad 100,864
    float*  invd    = (float*)(w + 100864);     // 100,000
    int*    ebuf    = w + 200864;               // 3,200,000
    int2*   pairbuf = (int2*)(w + 3400864);     // 3,200,000 int2 (6.4M words)
    ushort* xnbf    = (ushort*)(w + 9800864);   // N*128 bf16 (6.4M words)
    ushort* hbf     = (ushort*)(w + 16200864);  // N*128 bf16 (6.4M words)
    ushort* hnbf    = xnbf;  // reuse after agg1

    hipMemsetAsync(bhist, 0, 256 * sizeof(int), stream);
    hist_kernel<<<512, 256, 0, stream>>>(dst, bhist);
    scan_bkt<<<1, 256, 0, stream>>>(bhist, boff, gcur, rs);

    // layer-1 dual GEMM fused with phase-A edge binning
    megaA_kernel<<<NTILES * 9, 256, 0, stream>>>(x, W1s, W1n, b1, hbf, xnbf, src, dst,
                                                 gcur, pairbuf);
    bucket_kernel<<<NBKT, 256, 0, stream>>>(pairbuf, boff, rs, invd, ebuf);

    agg1_kernel<<<NNODES / 4, 256, 0, stream>>>(rs, ebuf, invd, xnbf, hbf);

    gemm2_dual_kernel<<<G1BLOCKS, 256, 0, stream>>>(hbf, W2s, W2n, b2, out, hnbf);
    agg2_kernel<<<NNODES / 8, 256, 0, stream>>>(rs, ebuf, invd, hnbf, out);
}

// Round 7
// 412.536 us; speedup vs baseline: 21.1403x; 1.0390x over previous
//
#include <hip/hip_runtime.h>

#define NNODES 100000
#define NEDGES 3200000
#define NBKT 196        // buckets of 512 nodes (dst>>9)
#define NROWB 1563      // ceil(NNODES/64) 64-row GEMM blocks
#define NTILES 782      // ceil(NEDGES/4096) phase-A tiles

typedef unsigned int uint;
typedef unsigned short ushort;

// ---- bf16 pack/unpack (RNE) ----
__device__ inline uint pack_bf2(float a, float b) {
    uint ua = __float_as_uint(a);
    uint ub = __float_as_uint(b);
    ua = (ua + 0x7FFFu + ((ua >> 16) & 1u)) >> 16;
    ub = (ub + 0x7FFFu + ((ub >> 16) & 1u)) >> 16;
    return ua | (ub << 16);
}
__device__ inline float2 unpack_bf2(uint v) {
    float2 r;
    r.x = __uint_as_float(v << 16);
    r.y = __uint_as_float(v & 0xFFFF0000u);
    return r;
}

// ---------- phase 0: bucket histogram over dst ----------
__global__ __launch_bounds__(256) void hist_kernel(const int* __restrict__ dst,
                                                   int* __restrict__ bhist) {
    __shared__ int lh[NBKT];
    for (int i = threadIdx.x; i < NBKT; i += 256) lh[i] = 0;
    __syncthreads();
    const int n4 = NEDGES / 4;
    for (int i = blockIdx.x * 256 + threadIdx.x; i < n4; i += gridDim.x * 256) {
        const int4 d = ((const int4*)dst)[i];
        atomicAdd(&lh[d.x >> 9], 1);
        atomicAdd(&lh[d.y >> 9], 1);
        atomicAdd(&lh[d.z >> 9], 1);
        atomicAdd(&lh[d.w >> 9], 1);
    }
    __syncthreads();
    for (int i = threadIdx.x; i < NBKT; i += 256)
        if (lh[i]) atomicAdd(&bhist[i], lh[i]);
}

// ---------- scan buckets -> boff, init gcur; rs[N] = E ----------
__global__ __launch_bounds__(256) void scan_bkt(const int* __restrict__ bhist,
                                                int* __restrict__ boff,
                                                int* __restrict__ gcur,
                                                int* __restrict__ rs) {
    __shared__ int s[256];
    const int tid = threadIdx.x;
    const int v = (tid < NBKT) ? bhist[tid] : 0;
    s[tid] = v;
    __syncthreads();
    for (int ofs = 1; ofs < 256; ofs <<= 1) {
        int t = (tid >= ofs) ? s[tid - ofs] : 0;
        __syncthreads();
        s[tid] += t;
        __syncthreads();
    }
    const int excl = s[tid] - v;
    if (tid < NBKT) {
        boff[tid] = excl;
        gcur[tid] = excl;
    }
    if (tid == NBKT - 1) {
        boff[NBKT] = s[tid];
        rs[NNODES] = NEDGES;
    }
}

// ---------- megaA: layer-1 dual GEMM (4/5 blocks) + phase-A binning (1/5) ----------
// GEMM: 64 rows x 128 cols per block; thread = 8 rows x 4 cols.
// sW in bf16 (32KB) + sXT transposed f32 (32KB) = 64KB LDS -> 2 blocks/CU.
__global__ __launch_bounds__(256) void megaA_kernel(
    const float* __restrict__ x, const float* __restrict__ W1s,
    const float* __restrict__ W1n, const float* __restrict__ b1,
    ushort* __restrict__ hbf, ushort* __restrict__ xnbf,
    const int* __restrict__ src, const int* __restrict__ dst,
    int* __restrict__ gcur, int2* __restrict__ pairbuf) {
    __shared__ int smem[16384];  // 64 KB
    const int bid = blockIdx.x;
    const int tid = threadIdx.x;

    if ((bid % 5) == 4) {
        // ---------- bin branch: 16 edges/thread in registers ----------
        int* lhist = smem;         // 256
        int* lofs = smem + 256;    // 256
        int* gbl = smem + 512;     // 256
        int* lcur = smem + 768;    // 256
        const int t = bid / 5;
        const int ebase = t * 4096;
        const int n = min(4096, NEDGES - ebase);
        const int nv4 = n >> 2;
        lhist[tid] = 0;
        lcur[tid] = 0;
        __syncthreads();
        int4 sv[4], dv[4];
#pragma unroll
        for (int u = 0; u < 4; ++u) {
            const int i4 = tid + 256 * u;
            if (i4 < nv4) {
                sv[u] = ((const int4*)(src + ebase))[i4];
                dv[u] = ((const int4*)(dst + ebase))[i4];
                atomicAdd(&lhist[dv[u].x >> 9], 1);
                atomicAdd(&lhist[dv[u].y >> 9], 1);
                atomicAdd(&lhist[dv[u].z >> 9], 1);
                atomicAdd(&lhist[dv[u].w >> 9], 1);
            }
        }
        __syncthreads();
        const int v = lhist[tid];
        lofs[tid] = v;
        __syncthreads();
        for (int ofs = 1; ofs < 256; ofs <<= 1) {
            int tv = (tid >= ofs) ? lofs[tid - ofs] : 0;
            __syncthreads();
            lofs[tid] += tv;
            __syncthreads();
        }
        if (tid < NBKT && v > 0) gbl[tid] = atomicAdd(&gcur[tid], v);
        __syncthreads();
#pragma unroll
        for (int u = 0; u < 4; ++u) {
            const int i4 = tid + 256 * u;
            if (i4 < nv4) {
                const int ss[4] = {sv[u].x, sv[u].y, sv[u].z, sv[u].w};
                const int dd[4] = {dv[u].x, dv[u].y, dv[u].z, dv[u].w};
#pragma unroll
                for (int j = 0; j < 4; ++j) {
                    const int b = dd[j] >> 9;
                    const int p = atomicAdd(&lcur[b], 1);
                    pairbuf[gbl[b] + p] = make_int2(ss[j], dd[j]);
                }
            }
        }
        return;
    }

    // ---------- GEMM branch ----------
    ushort* sW = (ushort*)smem;            // 128*128 bf16 = 32KB
    float* sXT = (float*)(smem + 8192);    // 128*64 f32 = 32KB
    const int g = (bid / 5) * 4 + (bid % 5);
    if (g >= 2 * NROWB) return;
    const bool self = g < NROWB;
    const float* __restrict__ W = self ? W1s : W1n;
    ushort* __restrict__ Y = self ? hbf : xnbf;
    const int rowbase = (self ? g : g - NROWB) * 64;

    for (int idx = tid * 4; idx < 128 * 128; idx += 1024) {
        const float4 wv = *(const float4*)&W[idx];
        uint2 p;
        p.x = pack_bf2(wv.x, wv.y);
        p.y = pack_bf2(wv.z, wv.w);
        *(uint2*)&sW[idx] = p;
    }
    {
        const int r = tid & 63;
        const int k0 = (tid >> 6) * 4;  // {0,4,8,12}
        const int row = min(rowbase + r, NNODES - 1);
#pragma unroll
        for (int kk = 0; kk < 128; kk += 16) {
            const float4 v = *(const float4*)&x[(size_t)row * 128 + kk + k0];
            sXT[(kk + k0 + 0) * 64 + r] = v.x;
            sXT[(kk + k0 + 1) * 64 + r] = v.y;
            sXT[(kk + k0 + 2) * 64 + r] = v.z;
            sXT[(kk + k0 + 3) * 64 + r] = v.w;
        }
    }
    __syncthreads();

    const int c4 = (tid & 31) * 4;   // 128 cols / 4
    const int r0 = (tid >> 5) * 8;   // 64 rows / 8
    float acc[8][4];
    if (self) {
        const float4 bv = *(const float4*)&b1[c4];
#pragma unroll
        for (int i = 0; i < 8; ++i) {
            acc[i][0] = bv.x; acc[i][1] = bv.y; acc[i][2] = bv.z; acc[i][3] = bv.w;
        }
    } else {
#pragma unroll
        for (int i = 0; i < 8; ++i)
#pragma unroll
            for (int j = 0; j < 4; ++j) acc[i][j] = 0.0f;
    }
#pragma unroll 4
    for (int k = 0; k < 128; ++k) {
        const uint2 wp = *(const uint2*)&sW[k * 128 + c4];
        const float2 wa = unpack_bf2(wp.x);
        const float2 wb = unpack_bf2(wp.y);
        const float4 xa = *(const float4*)&sXT[k * 64 + r0];
        const float4 xb = *(const float4*)&sXT[k * 64 + r0 + 4];
        const float xr[8] = {xa.x, xa.y, xa.z, xa.w, xb.x, xb.y, xb.z, xb.w};
#pragma unroll
        for (int i = 0; i < 8; ++i) {
            acc[i][0] = fmaf(xr[i], wa.x, acc[i][0]);
            acc[i][1] = fmaf(xr[i], wa.y, acc[i][1]);
            acc[i][2] = fmaf(xr[i], wb.x, acc[i][2]);
            acc[i][3] = fmaf(xr[i], wb.y, acc[i][3]);
        }
    }
#pragma unroll
    for (int i = 0; i < 8; ++i) {
        const int row = rowbase + r0 + i;
        if (row < NNODES) {
            uint2 o;
            o.x = pack_bf2(acc[i][0], acc[i][1]);
            o.y = pack_bf2(acc[i][2], acc[i][3]);
            *(uint2*)&Y[(size_t)row * 128 + c4] = o;
        }
    }
}

// ---------- phase B: per-bucket CSR finalize (deg/invd/rs/ebuf) ----------
__global__ __launch_bounds__(256) void bucket_kernel(const int2* __restrict__ pairbuf,
                                                     const int* __restrict__ boff,
                                                     int* __restrict__ rs,
                                                     float* __restrict__ invd,
                                                     int* __restrict__ ebuf) {
    __shared__ int ndeg[512];
    __shared__ int nofs[512];
    __shared__ int lcur[512];
    __shared__ int sps[256];
    const int b = blockIdx.x;
    const int tid = threadIdx.x;
    const int nb = b << 9;
    const int ln = min(512, NNODES - nb);
    const int base = boff[b];
    const int cnt = boff[b + 1] - base;
    for (int i = tid; i < 512; i += 256) {
        ndeg[i] = 0;
        lcur[i] = 0;
    }
    __syncthreads();
    for (int i = tid; i < cnt; i += 256) {
        const int2 e = pairbuf[base + i];
        atomicAdd(&ndeg[e.y - nb], 1);
    }
    __syncthreads();
    for (int nidx = tid; nidx < ln; nidx += 256)
        invd[nb + nidx] = 1.0f / fmaxf((float)ndeg[nidx], 1.0f);
    const int a0 = ndeg[2 * tid];
    const int a1 = ndeg[2 * tid + 1];
    sps[tid] = a0 + a1;
    __syncthreads();
    for (int ofs = 1; ofs < 256; ofs <<= 1) {
        int t = (tid >= ofs) ? sps[tid - ofs] : 0;
        __syncthreads();
        sps[tid] += t;
        __syncthreads();
    }
    const int excl = sps[tid] - (a0 + a1);
    nofs[2 * tid] = excl;
    nofs[2 * tid + 1] = excl + a0;
    __syncthreads();
    for (int nidx = tid; nidx < ln; nidx += 256) rs[nb + nidx] = base + nofs[nidx];
    for (int i = tid; i < cnt; i += 256) {
        const int2 e = pairbuf[base + i];
        const int nn = e.y - nb;
        const int p = atomicAdd(&lcur[nn], 1);
        ebuf[base + nofs[nn] + p] = e.x;
    }
}

// ---------- layer-2 dual GEMM: out = h@W2s + b2 (f32) ; hn = h@W2n (bf16) ----------
// 64 rows x 128 cols (64 self | 64 neigh); thread = 8 rows x 4 cols.
__global__ __launch_bounds__(256) void gemm2_dual_kernel(
    const ushort* __restrict__ hbf, const float* __restrict__ W2s,
    const float* __restrict__ W2n, const float* __restrict__ b2,
    float* __restrict__ out, ushort* __restrict__ hnbf) {
    __shared__ ushort sW[128 * 128];  // bf16, 32KB
    __shared__ float sXT[128 * 64];   // 32KB
    const int tid = threadIdx.x;
    const int rowbase = blockIdx.x * 64;
    for (int idx = tid * 4; idx < 128 * 128; idx += 1024) {
        const int k = idx >> 7, col = idx & 127;
        const float* srcp = (col < 64) ? &W2s[k * 64 + col] : &W2n[k * 64 + (col - 64)];
        const float4 wv = *(const float4*)srcp;
        uint2 p;
        p.x = pack_bf2(wv.x, wv.y);
        p.y = pack_bf2(wv.z, wv.w);
        *(uint2*)&sW[idx] = p;
    }
    {
        const int r = tid & 63;
        const int k0 = (tid >> 6) * 4;
        const int row = min(rowbase + r, NNODES - 1);
#pragma unroll
        for (int kk = 0; kk < 128; kk += 16) {
            const uint2 hv = *(const uint2*)&hbf[(size_t)row * 128 + kk + k0];
            const float2 a = unpack_bf2(hv.x);
            const float2 b = unpack_bf2(hv.y);
            sXT[(kk + k0 + 0) * 64 + r] = a.x;
            sXT[(kk + k0 + 1) * 64 + r] = a.y;
            sXT[(kk + k0 + 2) * 64 + r] = b.x;
            sXT[(kk + k0 + 3) * 64 + r] = b.y;
        }
    }
    __syncthreads();

    const int c4 = (tid & 31) * 4;
    const int r0 = (tid >> 5) * 8;
    const bool isself = (tid & 31) < 16;
    float acc[8][4];
    if (isself) {
        const float4 bv = *(const float4*)&b2[c4];
#pragma unroll
        for (int i = 0; i < 8; ++i) {
            acc[i][0] = bv.x; acc[i][1] = bv.y; acc[i][2] = bv.z; acc[i][3] = bv.w;
        }
    } else {
#pragma unroll
        for (int i = 0; i < 8; ++i)
#pragma unroll
            for (int j = 0; j < 4; ++j) acc[i][j] = 0.0f;
    }
#pragma unroll 4
    for (int k = 0; k < 128; ++k) {
        const uint2 wp = *(const uint2*)&sW[k * 128 + c4];
        const float2 wa = unpack_bf2(wp.x);
        const float2 wb = unpack_bf2(wp.y);
        const float4 xa = *(const float4*)&sXT[k * 64 + r0];
        const float4 xb = *(const float4*)&sXT[k * 64 + r0 + 4];
        const float xr[8] = {xa.x, xa.y, xa.z, xa.w, xb.x, xb.y, xb.z, xb.w};
#pragma unroll
        for (int i = 0; i < 8; ++i) {
            acc[i][0] = fmaf(xr[i], wa.x, acc[i][0]);
            acc[i][1] = fmaf(xr[i], wa.y, acc[i][1]);
            acc[i][2] = fmaf(xr[i], wb.x, acc[i][2]);
            acc[i][3] = fmaf(xr[i], wb.y, acc[i][3]);
        }
    }
#pragma unroll
    for (int i = 0; i < 8; ++i) {
        const int row = rowbase + r0 + i;
        if (row < NNODES) {
            if (isself) {
                float4 o;
                o.x = acc[i][0]; o.y = acc[i][1]; o.z = acc[i][2]; o.w = acc[i][3];
                *(float4*)&out[(size_t)row * 64 + c4] = o;
            } else {
                uint2 o;
                o.x = pack_bf2(acc[i][0], acc[i][1]);
                o.y = pack_bf2(acc[i][2], acc[i][3]);
                *(uint2*)&hnbf[(size_t)row * 64 + (c4 - 64)] = o;
            }
        }
    }
}

// ---------- layer-1 aggregation ----------
__global__ __launch_bounds__(256) void agg1_kernel(const int* __restrict__ rs,
                                                   const int* __restrict__ ebuf,
                                                   const float* __restrict__ invd,
                                                   const ushort* __restrict__ xnbf,
                                                   ushort* __restrict__ hbf) {
    const int node = blockIdx.x * 4 + (threadIdx.x >> 6);
    if (node >= NNODES) return;
    const int lane = threadIdx.x & 63;
    const int beg = rs[node];
    const int end = rs[node + 1];
    const uint* fp = (const uint*)xnbf + lane;
    float ax = 0.0f, ay = 0.0f;
    int i = beg;
    for (; i + 7 < end; i += 8) {
#pragma unroll
        for (int u = 0; u < 8; ++u) {
            const float2 v = unpack_bf2(fp[(size_t)ebuf[i + u] * 64]);
            ax += v.x;
            ay += v.y;
        }
    }
    for (; i < end; ++i) {
        const float2 v = unpack_bf2(fp[(size_t)ebuf[i] * 64]);
        ax += v.x;
        ay += v.y;
    }
    const float w = invd[node];
    uint* hp = (uint*)hbf + (size_t)node * 64 + lane;
    const float2 hv = unpack_bf2(*hp);
    const float rx = fmaxf(fmaf(w, ax, hv.x), 0.0f);
    const float ry = fmaxf(fmaf(w, ay, hv.y), 0.0f);
    *hp = pack_bf2(rx, ry);
}

// ---------- layer-2 aggregation ----------
__global__ __launch_bounds__(256) void agg2_kernel(const int* __restrict__ rs,
                                                   const int* __restrict__ ebuf,
                                                   const float* __restrict__ invd,
                                                   const ushort* __restrict__ hnbf,
                                                   float* __restrict__ out) {
    const int node = blockIdx.x * 8 + (threadIdx.x >> 5);
    if (node >= NNODES) return;
    const int lane = threadIdx.x & 31;
    const int beg = rs[node];
    const int end = rs[node + 1];
    const uint* fp = (const uint*)hnbf + lane;
    float ax = 0.0f, ay = 0.0f;
    int i = beg;
    for (; i + 7 < end; i += 8) {
#pragma unroll
        for (int u = 0; u < 8; ++u) {
            const float2 v = unpack_bf2(fp[(size_t)ebuf[i + u] * 32]);
            ax += v.x;
            ay += v.y;
        }
    }
    for (; i < end; ++i) {
        const float2 v = unpack_bf2(fp[(size_t)ebuf[i] * 32]);
        ax += v.x;
        ay += v.y;
    }
    const float w = invd[node];
    float2* op = (float2*)&out[(size_t)node * 64 + lane * 2];
    float2 ov = *op;
    ov.x = fmaf(w, ax, ov.x);
    ov.y = fmaf(w, ay, ov.y);
    *op = ov;
}

extern "C" void kernel_launch(void* const* d_in, const int* in_sizes, int n_in,
                              void* d_out, int out_size, void* d_ws, size_t ws_size,
                              hipStream_t stream) {
    const float* x   = (const float*)d_in[0];
    const int*   ei  = (const int*)d_in[1];
    const float* W1s = (const float*)d_in[2];
    const float* W1n = (const float*)d_in[3];
    const float* b1  = (const float*)d_in[4];
    const float* W2s = (const float*)d_in[5];
    const float* W2n = (const float*)d_in[6];
    const float* b2  = (const float*)d_in[7];
    float* out = (float*)d_out;

    const int* src = ei;           // edge_index row 0
    const int* dst = ei + NEDGES;  // edge_index row 1

    // workspace carve-up (word offsets)
    int* w = (int*)d_ws;
    int*    bhist   = w;                        // 256
    int*    boff    = w + 256;                  // 256 (need 197)
    int*    gcur    = w + 512;                  // 256
    int*    rs      = w + 768;                  // 100,001 -> pad 100,864
    float*  invd    = (float*)(w + 100864);     // 100,000
    int*    ebuf    = w + 200864;               // 3,200,000
    int2*   pairbuf = (int2*)(w + 3400864);     // 3,200,000 int2 (6.4M words)
    ushort* xnbf    = (ushort*)(w + 9800864);   // N*128 bf16 (6.4M words)
    ushort* hbf     = (ushort*)(w + 16200864);  // N*128 bf16 (6.4M words)
    ushort* hnbf    = xnbf;  // reuse after agg1

    hipMemsetAsync(bhist, 0, 256 * sizeof(int), stream);
    hist_kernel<<<512, 256, 0, stream>>>(dst, bhist);
    scan_bkt<<<1, 256, 0, stream>>>(bhist, boff, gcur, rs);

    // layer-1 dual GEMM fused with phase-A edge binning
    megaA_kernel<<<NTILES * 5, 256, 0, stream>>>(x, W1s, W1n, b1, hbf, xnbf, src, dst,
                                                 gcur, pairbuf);
    bucket_kernel<<<NBKT, 256, 0, stream>>>(pairbuf, boff, rs, invd, ebuf);

    agg1_kernel<<<NNODES / 4, 256, 0, stream>>>(rs, ebuf, invd, xnbf, hbf);

    gemm2_dual_kernel<<<NROWB, 256, 0, stream>>>(hbf, W2s, W2n, b2, out, hnbf);
    agg2_kernel<<<NNODES / 8, 256, 0, stream>>>(rs, ebuf, invd, hnbf, out);
}

// Round 8
// 317.248 us; speedup vs baseline: 27.4900x; 1.3004x over previous
//
#include <hip/hip_runtime.h>

#define NNODES 100000
#define NEDGES 3200000
#define NBKT 196        // buckets of 512 nodes (dst>>9)
#define NTILES2 1563    // bin tiles of 2048 edges
#define NGB 1563        // ceil(NNODES/64) GEMM blocks

typedef unsigned int uint;
typedef unsigned short ushort;
typedef __attribute__((ext_vector_type(8))) short short8;   // 8 bf16 (4 VGPRs)
typedef __attribute__((ext_vector_type(4))) float f32x4;

__device__ inline ushort bf16_rne(float f) {
    uint u = __float_as_uint(f);
    return (ushort)((u + 0x7FFFu + ((u >> 16) & 1u)) >> 16);
}
__device__ inline uint pack_bf2(float a, float b) {
    return (uint)bf16_rne(a) | ((uint)bf16_rne(b) << 16);
}
__device__ inline float2 unpack_bf2(uint v) {
    float2 r;
    r.x = __uint_as_float(v << 16);
    r.y = __uint_as_float(v & 0xFFFF0000u);
    return r;
}

// ---------- phase 0: bucket histogram over dst ----------
__global__ __launch_bounds__(256) void hist_kernel(const int* __restrict__ dst,
                                                   int* __restrict__ bhist) {
    __shared__ int lh[NBKT];
    for (int i = threadIdx.x; i < NBKT; i += 256) lh[i] = 0;
    __syncthreads();
    const int n4 = NEDGES / 4;
    for (int i = blockIdx.x * 256 + threadIdx.x; i < n4; i += gridDim.x * 256) {
        const int4 d = ((const int4*)dst)[i];
        atomicAdd(&lh[d.x >> 9], 1);
        atomicAdd(&lh[d.y >> 9], 1);
        atomicAdd(&lh[d.z >> 9], 1);
        atomicAdd(&lh[d.w >> 9], 1);
    }
    __syncthreads();
    for (int i = threadIdx.x; i < NBKT; i += 256)
        if (lh[i]) atomicAdd(&bhist[i], lh[i]);
}

// ---------- scan buckets -> boff, init gcur; rs[N] = E ----------
__global__ __launch_bounds__(256) void scan_bkt(const int* __restrict__ bhist,
                                                int* __restrict__ boff,
                                                int* __restrict__ gcur,
                                                int* __restrict__ rs) {
    __shared__ int s[256];
    const int tid = threadIdx.x;
    const int v = (tid < NBKT) ? bhist[tid] : 0;
    s[tid] = v;
    __syncthreads();
    for (int ofs = 1; ofs < 256; ofs <<= 1) {
        int t = (tid >= ofs) ? s[tid - ofs] : 0;
        __syncthreads();
        s[tid] += t;
        __syncthreads();
    }
    const int excl = s[tid] - v;
    if (tid < NBKT) {
        boff[tid] = excl;
        gcur[tid] = excl;
    }
    if (tid == NBKT - 1) {
        boff[NBKT] = s[tid];
        rs[NNODES] = NEDGES;
    }
}

// ---------- prep: transpose weights to bf16 W^T in workspace ----------
// wt[0]=W1s^T, wt[1]=W1n^T, wt[2]=[W2s|W2n]^T  (each [128 cols][128 k] bf16)
__global__ __launch_bounds__(256) void prep_kernel(const float* __restrict__ W1s,
                                                   const float* __restrict__ W1n,
                                                   const float* __restrict__ W2s,
                                                   const float* __restrict__ W2n,
                                                   ushort* __restrict__ wt) {
    const int id = blockIdx.x * 256 + threadIdx.x;  // 0..49151
    const int m = id >> 14;
    const int r = id & 16383;
    const int c = r >> 7;
    const int k = r & 127;
    float v;
    if (m == 0) v = W1s[k * 128 + c];
    else if (m == 1) v = W1n[k * 128 + c];
    else v = (c < 64) ? W2s[k * 64 + c] : W2n[k * 64 + (c - 64)];
    wt[id] = bf16_rne(v);
}

// ---------- megaA: MFMA dual GEMM1 (even blocks) + edge binning (odd) ----------
// GEMM: 64 rows/block, 4 waves x 16 rows; x split hi/lo bf16 (full precision);
// W^T bf16 in LDS, chunk-XOR swizzled (kchunk ^= col&15) for conflict-free b128.
__global__ __launch_bounds__(256) void megaA_kernel(
    const float* __restrict__ x, const ushort* __restrict__ wt,
    const float* __restrict__ b1, ushort* __restrict__ hbf,
    ushort* __restrict__ xnbf, const int* __restrict__ src,
    const int* __restrict__ dst, int* __restrict__ gcur,
    int2* __restrict__ pairbuf) {
    __shared__ uint4 sWq[4096];  // 64 KB: [2][128 cols][16 chunks of 8 bf16]
    const int bid = blockIdx.x;
    const int tid = threadIdx.x;

    if (bid & 1) {
        // ---------- bin branch: 2048 edges, 8/thread in registers ----------
        int* ib = (int*)sWq;
        int* lhist = ib;
        int* lofs = ib + 256;
        int* gbl = ib + 512;
        int* lcur = ib + 768;
        const int t = bid >> 1;
        const int ebase = t * 2048;
        const int n = min(2048, NEDGES - ebase);
        const int nv4 = n >> 2;
        lhist[tid] = 0;
        lcur[tid] = 0;
        __syncthreads();
        int4 sv[2], dv[2];
#pragma unroll
        for (int u = 0; u < 2; ++u) {
            const int i4 = tid + 256 * u;
            if (i4 < nv4) {
                sv[u] = ((const int4*)(src + ebase))[i4];
                dv[u] = ((const int4*)(dst + ebase))[i4];
                atomicAdd(&lhist[dv[u].x >> 9], 1);
                atomicAdd(&lhist[dv[u].y >> 9], 1);
                atomicAdd(&lhist[dv[u].z >> 9], 1);
                atomicAdd(&lhist[dv[u].w >> 9], 1);
            }
        }
        __syncthreads();
        const int v = lhist[tid];
        lofs[tid] = v;
        __syncthreads();
        for (int ofs = 1; ofs < 256; ofs <<= 1) {
            int tv = (tid >= ofs) ? lofs[tid - ofs] : 0;
            __syncthreads();
            lofs[tid] += tv;
            __syncthreads();
        }
        if (tid < NBKT && v > 0) gbl[tid] = atomicAdd(&gcur[tid], v);
        __syncthreads();
#pragma unroll
        for (int u = 0; u < 2; ++u) {
            const int i4 = tid + 256 * u;
            if (i4 < nv4) {
                const int ss[4] = {sv[u].x, sv[u].y, sv[u].z, sv[u].w};
                const int dd[4] = {dv[u].x, dv[u].y, dv[u].z, dv[u].w};
#pragma unroll
                for (int j = 0; j < 4; ++j) {
                    const int b = dd[j] >> 9;
                    const int p = atomicAdd(&lcur[b], 1);
                    pairbuf[gbl[b] + p] = make_int2(ss[j], dd[j]);
                }
            }
        }
        return;
    }

    // ---------- GEMM branch ----------
    const int g = bid >> 1;  // 0..NGB-1
#pragma unroll
    for (int i = 0; i < 16; ++i) {
        const int cid = tid + 256 * i;  // chunk id over 2 W matrices
        const int kc = cid & 15;
        const int c = (cid >> 4) & 127;
        const int wsel = cid >> 11;
        sWq[wsel * 2048 + c * 16 + (kc ^ (c & 15))] = *(const uint4*)&wt[cid * 8];
    }
    const int w = tid >> 6;   // wave 0..3
    const int l = tid & 63;
    const int lg = l >> 4;    // lane group
    const int lr = l & 15;    // row-in-strip / col-in-tile
    const int rowbase = g * 64;
    const int arow = min(rowbase + w * 16 + lr, NNODES - 1);
    const float* xrow = x + (size_t)arow * 128;
    short8 ahi[4], alo[4];
#pragma unroll
    for (int ks = 0; ks < 4; ++ks) {
        const float4 va = *(const float4*)&xrow[ks * 32 + lg * 8];
        const float4 vb = *(const float4*)&xrow[ks * 32 + lg * 8 + 4];
        const float vv[8] = {va.x, va.y, va.z, va.w, vb.x, vb.y, vb.z, vb.w};
        short8 h8, l8;
#pragma unroll
        for (int j = 0; j < 8; ++j) {
            const ushort hu = bf16_rne(vv[j]);
            h8[j] = (short)hu;
            l8[j] = (short)bf16_rne(vv[j] - __uint_as_float((uint)hu << 16));
        }
        ahi[ks] = h8;
        alo[ks] = l8;
    }
    __syncthreads();

#pragma unroll
    for (int wsel = 0; wsel < 2; ++wsel) {
        ushort* __restrict__ Y = wsel ? xnbf : hbf;
#pragma unroll
        for (int ct = 0; ct < 8; ++ct) {
            f32x4 acc;
            if (wsel == 0) {
                const float bv = b1[ct * 16 + lr];
                acc = (f32x4){bv, bv, bv, bv};
            } else {
                acc = (f32x4){0.0f, 0.0f, 0.0f, 0.0f};
            }
            const int cbase = wsel * 2048 + (ct * 16 + lr) * 16;
#pragma unroll
            for (int ks = 0; ks < 4; ++ks) {
                const short8 bf =
                    *(const short8*)&sWq[cbase + ((4 * ks + lg) ^ lr)];
                acc = __builtin_amdgcn_mfma_f32_16x16x32_bf16(ahi[ks], bf, acc, 0, 0, 0);
                acc = __builtin_amdgcn_mfma_f32_16x16x32_bf16(alo[ks], bf, acc, 0, 0, 0);
            }
#pragma unroll
            for (int r_ = 0; r_ < 4; ++r_) {
                const int orow = rowbase + w * 16 + lg * 4 + r_;
                if (orow < NNODES)
                    Y[(size_t)orow * 128 + ct * 16 + lr] = bf16_rne(acc[r_]);
            }
        }
    }
}

// ---------- phase B: per-bucket CSR finalize (deg/invd/rs/ebuf) ----------
__global__ __launch_bounds__(256) void bucket_kernel(const int2* __restrict__ pairbuf,
                                                     const int* __restrict__ boff,
                                                     int* __restrict__ rs,
                                                     float* __restrict__ invd,
                                                     int* __restrict__ ebuf) {
    __shared__ int ndeg[512];
    __shared__ int nofs[512];
    __shared__ int lcur[512];
    __shared__ int sps[256];
    const int b = blockIdx.x;
    const int tid = threadIdx.x;
    const int nb = b << 9;
    const int ln = min(512, NNODES - nb);
    const int base = boff[b];
    const int cnt = boff[b + 1] - base;
    for (int i = tid; i < 512; i += 256) {
        ndeg[i] = 0;
        lcur[i] = 0;
    }
    __syncthreads();
    for (int i = tid; i < cnt; i += 256) {
        const int2 e = pairbuf[base + i];
        atomicAdd(&ndeg[e.y - nb], 1);
    }
    __syncthreads();
    for (int nidx = tid; nidx < ln; nidx += 256)
        invd[nb + nidx] = 1.0f / fmaxf((float)ndeg[nidx], 1.0f);
    const int a0 = ndeg[2 * tid];
    const int a1 = ndeg[2 * tid + 1];
    sps[tid] = a0 + a1;
    __syncthreads();
    for (int ofs = 1; ofs < 256; ofs <<= 1) {
        int t = (tid >= ofs) ? sps[tid - ofs] : 0;
        __syncthreads();
        sps[tid] += t;
        __syncthreads();
    }
    const int excl = sps[tid] - (a0 + a1);
    nofs[2 * tid] = excl;
    nofs[2 * tid + 1] = excl + a0;
    __syncthreads();
    for (int nidx = tid; nidx < ln; nidx += 256) rs[nb + nidx] = base + nofs[nidx];
    for (int i = tid; i < cnt; i += 256) {
        const int2 e = pairbuf[base + i];
        const int nn = e.y - nb;
        const int p = atomicAdd(&lcur[nn], 1);
        ebuf[base + nofs[nn] + p] = e.x;
    }
}

// ---------- layer-2 dual GEMM (MFMA): out = h@W2s + b2 (f32) ; hn = h@W2n (bf16) --
__global__ __launch_bounds__(256) void gemm2_dual_kernel(
    const ushort* __restrict__ hbf, const ushort* __restrict__ wt2,
    const float* __restrict__ b2, float* __restrict__ out,
    ushort* __restrict__ hnbf) {
    __shared__ uint4 sWq[2048];  // 32 KB: [128 cols][16 chunks] swizzled
    const int tid = threadIdx.x;
#pragma unroll
    for (int i = 0; i < 8; ++i) {
        const int cid = tid + 256 * i;  // 0..2047
        const int kc = cid & 15;
        const int c = cid >> 4;
        sWq[c * 16 + (kc ^ (c & 15))] = *(const uint4*)&wt2[cid * 8];
    }
    const int w = tid >> 6;
    const int l = tid & 63;
    const int lg = l >> 4;
    const int lr = l & 15;
    const int rowbase = blockIdx.x * 64;
    const int arow = min(rowbase + w * 16 + lr, NNODES - 1);
    const ushort* hrow = hbf + (size_t)arow * 128;
    short8 a[4];
#pragma unroll
    for (int ks = 0; ks < 4; ++ks) a[ks] = *(const short8*)&hrow[ks * 32 + lg * 8];
    __syncthreads();

#pragma unroll
    for (int ct = 0; ct < 8; ++ct) {
        f32x4 acc;
        if (ct < 4) {
            const float bv = b2[ct * 16 + lr];
            acc = (f32x4){bv, bv, bv, bv};
        } else {
            acc = (f32x4){0.0f, 0.0f, 0.0f, 0.0f};
        }
        const int cbase = (ct * 16 + lr) * 16;
#pragma unroll
        for (int ks = 0; ks < 4; ++ks) {
            const short8 bf = *(const short8*)&sWq[cbase + ((4 * ks + lg) ^ lr)];
            acc = __builtin_amdgcn_mfma_f32_16x16x32_bf16(a[ks], bf, acc, 0, 0, 0);
        }
#pragma unroll
        for (int r_ = 0; r_ < 4; ++r_) {
            const int orow = rowbase + w * 16 + lg * 4 + r_;
            if (orow < NNODES) {
                if (ct < 4) {
                    out[(size_t)orow * 64 + ct * 16 + lr] = acc[r_];
                } else {
                    hnbf[(size_t)orow * 64 + (ct - 4) * 16 + lr] = bf16_rne(acc[r_]);
                }
            }
        }
    }
}

// ---------- layer-1 aggregation ----------
__global__ __launch_bounds__(256) void agg1_kernel(const int* __restrict__ rs,
                                                   const int* __restrict__ ebuf,
                                                   const float* __restrict__ invd,
                                                   const ushort* __restrict__ xnbf,
                                                   ushort* __restrict__ hbf) {
    const int node = blockIdx.x * 4 + (threadIdx.x >> 6);
    if (node >= NNODES) return;
    const int lane = threadIdx.x & 63;
    const int beg = rs[node];
    const int end = rs[node + 1];
    const uint* fp = (const uint*)xnbf + lane;
    float ax = 0.0f, ay = 0.0f;
    int i = beg;
    for (; i + 7 < end; i += 8) {
#pragma unroll
        for (int u = 0; u < 8; ++u) {
            const float2 v = unpack_bf2(fp[(size_t)ebuf[i + u] * 64]);
            ax += v.x;
            ay += v.y;
        }
    }
    for (; i < end; ++i) {
        const float2 v = unpack_bf2(fp[(size_t)ebuf[i] * 64]);
        ax += v.x;
        ay += v.y;
    }
    const float w = invd[node];
    uint* hp = (uint*)hbf + (size_t)node * 64 + lane;
    const float2 hv = unpack_bf2(*hp);
    const float rx = fmaxf(fmaf(w, ax, hv.x), 0.0f);
    const float ry = fmaxf(fmaf(w, ay, hv.y), 0.0f);
    *hp = pack_bf2(rx, ry);
}

// ---------- layer-2 aggregation ----------
__global__ __launch_bounds__(256) void agg2_kernel(const int* __restrict__ rs,
                                                   const int* __restrict__ ebuf,
                                                   const float* __restrict__ invd,
                                                   const ushort* __restrict__ hnbf,
                                                   float* __restrict__ out) {
    const int node = blockIdx.x * 8 + (threadIdx.x >> 5);
    if (node >= NNODES) return;
    const int lane = threadIdx.x & 31;
    const int beg = rs[node];
    const int end = rs[node + 1];
    const uint* fp = (const uint*)hnbf + lane;
    float ax = 0.0f, ay = 0.0f;
    int i = beg;
    for (; i + 7 < end; i += 8) {
#pragma unroll
        for (int u = 0; u < 8; ++u) {
            const float2 v = unpack_bf2(fp[(size_t)ebuf[i + u] * 32]);
            ax += v.x;
            ay += v.y;
        }
    }
    for (; i < end; ++i) {
        const float2 v = unpack_bf2(fp[(size_t)ebuf[i] * 32]);
        ax += v.x;
        ay += v.y;
    }
    const float w = invd[node];
    float2* op = (float2*)&out[(size_t)node * 64 + lane * 2];
    float2 ov = *op;
    ov.x = fmaf(w, ax, ov.x);
    ov.y = fmaf(w, ay, ov.y);
    *op = ov;
}

extern "C" void kernel_launch(void* const* d_in, const int* in_sizes, int n_in,
                              void* d_out, int out_size, void* d_ws, size_t ws_size,
                              hipStream_t stream) {
    const float* x   = (const float*)d_in[0];
    const int*   ei  = (const int*)d_in[1];
    const float* W1s = (const float*)d_in[2];
    const float* W1n = (const float*)d_in[3];
    const float* b1  = (const float*)d_in[4];
    const float* W2s = (const float*)d_in[5];
    const float* W2n = (const float*)d_in[6];
    const float* b2  = (const float*)d_in[7];
    float* out = (float*)d_out;

    const int* src = ei;           // edge_index row 0
    const int* dst = ei + NEDGES;  // edge_index row 1

    // workspace carve-up (word offsets)
    int* w = (int*)d_ws;
    int*    bhist   = w;                        // 256
    int*    boff    = w + 256;                  // 256 (need 197)
    int*    gcur    = w + 512;                  // 256
    int*    rs      = w + 768;                  // 100,001 -> pad 100,864
    float*  invd    = (float*)(w + 100864);     // 100,000
    int*    ebuf    = w + 200864;               // 3,200,000
    int2*   pairbuf = (int2*)(w + 3400864);     // 3,200,000 int2 (6.4M words)
    ushort* xnbf    = (ushort*)(w + 9800864);   // N*128 bf16 (6.4M words)
    ushort* hbf     = (ushort*)(w + 16200864);  // N*128 bf16 (6.4M words)
    ushort* wtbuf   = (ushort*)(w + 22600864);  // 49,152 ushorts (24,576 words)
    ushort* hnbf    = xnbf;  // reuse after agg1

    hipMemsetAsync(bhist, 0, 256 * sizeof(int), stream);
    hist_kernel<<<512, 256, 0, stream>>>(dst, bhist);
    scan_bkt<<<1, 256, 0, stream>>>(bhist, boff, gcur, rs);
    prep_kernel<<<192, 256, 0, stream>>>(W1s, W1n, W2s, W2n, wtbuf);

    // layer-1 dual MFMA GEMM fused 1:1 with edge binning
    megaA_kernel<<<2 * NTILES2, 256, 0, stream>>>(x, wtbuf, b1, hbf, xnbf, src, dst,
                                                  gcur, pairbuf);
    bucket_kernel<<<NBKT, 256, 0, stream>>>(pairbuf, boff, rs, invd, ebuf);

    agg1_kernel<<<NNODES / 4, 256, 0, stream>>>(rs, ebuf, invd, xnbf, hbf);

    gemm2_dual_kernel<<<NGB, 256, 0, stream>>>(hbf, wtbuf + 32768, b2, out, hnbf);
    agg2_kernel<<<NNODES / 8, 256, 0, stream>>>(rs, ebuf, invd, hnbf, out);
}

// Round 9
// 273.376 us; speedup vs baseline: 31.9015x; 1.1605x over previous
//
#include <hip/hip_runtime.h>

#define NNODES 100000
#define NEDGES 3200000
#define NBKT 196        // buckets of 512 nodes (dst>>9)
#define NTILES2 1563    // bin tiles of 2048 edges
#define NGB 1563        // ceil(NNODES/64) GEMM blocks

typedef unsigned int uint;
typedef unsigned short ushort;
typedef unsigned char uchar;
typedef __attribute__((ext_vector_type(8))) short short8;   // 8 bf16 (4 VGPRs)
typedef __attribute__((ext_vector_type(4))) float f32x4;
typedef __attribute__((ext_vector_type(2))) float f32x2;

__device__ inline ushort bf16_rne(float f) {
    uint u = __float_as_uint(f);
    return (ushort)((u + 0x7FFFu + ((u >> 16) & 1u)) >> 16);
}
__device__ inline uint pack_bf2(float a, float b) {
    return (uint)bf16_rne(a) | ((uint)bf16_rne(b) << 16);
}
__device__ inline float2 unpack_bf2(uint v) {
    float2 r;
    r.x = __uint_as_float(v << 16);
    r.y = __uint_as_float(v & 0xFFFF0000u);
    return r;
}

// ---- fp8 e4m3fn (OCP) encode/decode; encoder flushes |v|<2^-6 to 0 ----
__device__ inline uchar f32_to_fp8(float f) {
    uint u = __float_as_uint(f);
    uint s = (u >> 24) & 0x80u;
    uint e = (u >> 23) & 0xFFu;
    if (e < 121u) return (uchar)s;  // flush to signed zero
    uint m = u & 0x7FFFFFu;
    uint r = (m + 0x7FFFFu + ((m >> 20) & 1u)) >> 20;  // RNE to 3 bits
    uint em = ((e - 120u) << 3) + r;                   // carry folds into exp
    return (uchar)(s | em);
}
__device__ inline float fp8_dec(uint b) {
    uint s = (b & 0x80u) << 24;
    uint em = b & 0x7Fu;
    float v = __uint_as_float(s | ((em + 960u) << 20));
    return em ? v : 0.0f;
}
__device__ inline float2 fp8_lo2(uint pk) {
#if __has_builtin(__builtin_amdgcn_cvt_pk_f32_fp8)
    f32x2 r = __builtin_amdgcn_cvt_pk_f32_fp8((int)pk, false);
    return make_float2(r[0], r[1]);
#else
    return make_float2(fp8_dec(pk & 0xFFu), fp8_dec((pk >> 8) & 0xFFu));
#endif
}
__device__ inline float2 fp8_hi2(uint pk) {
#if __has_builtin(__builtin_amdgcn_cvt_pk_f32_fp8)
    f32x2 r = __builtin_amdgcn_cvt_pk_f32_fp8((int)pk, true);
    return make_float2(r[0], r[1]);
#else
    return make_float2(fp8_dec((pk >> 16) & 0xFFu), fp8_dec(pk >> 24));
#endif
}

// ---------- phase 0: bucket histogram over dst + weight prep (fused) ----------
// blocks 0..511: histogram; blocks 512..703: W^T bf16 prep
__global__ __launch_bounds__(256) void histprep_kernel(
    const int* __restrict__ dst, int* __restrict__ bhist,
    const float* __restrict__ W1s, const float* __restrict__ W1n,
    const float* __restrict__ W2s, const float* __restrict__ W2n,
    ushort* __restrict__ wt) {
    if (blockIdx.x >= 512) {
        const int id = (blockIdx.x - 512) * 256 + threadIdx.x;  // 0..49151
        const int m = id >> 14;
        const int r = id & 16383;
        const int c = r >> 7;
        const int k = r & 127;
        float v;
        if (m == 0) v = W1s[k * 128 + c];
        else if (m == 1) v = W1n[k * 128 + c];
        else v = (c < 64) ? W2s[k * 64 + c] : W2n[k * 64 + (c - 64)];
        wt[id] = bf16_rne(v);
        return;
    }
    __shared__ int lh[NBKT];
    for (int i = threadIdx.x; i < NBKT; i += 256) lh[i] = 0;
    __syncthreads();
    const int n4 = NEDGES / 4;
    for (int i = blockIdx.x * 256 + threadIdx.x; i < n4; i += 512 * 256) {
        const int4 d = ((const int4*)dst)[i];
        atomicAdd(&lh[d.x >> 9], 1);
        atomicAdd(&lh[d.y >> 9], 1);
        atomicAdd(&lh[d.z >> 9], 1);
        atomicAdd(&lh[d.w >> 9], 1);
    }
    __syncthreads();
    for (int i = threadIdx.x; i < NBKT; i += 256)
        if (lh[i]) atomicAdd(&bhist[i], lh[i]);
}

// ---------- scan buckets -> boff, init gcur; rs[N] = E ----------
__global__ __launch_bounds__(256) void scan_bkt(const int* __restrict__ bhist,
                                                int* __restrict__ boff,
                                                int* __restrict__ gcur,
                                                int* __restrict__ rs) {
    __shared__ int s[256];
    const int tid = threadIdx.x;
    const int v = (tid < NBKT) ? bhist[tid] : 0;
    s[tid] = v;
    __syncthreads();
    for (int ofs = 1; ofs < 256; ofs <<= 1) {
        int t = (tid >= ofs) ? s[tid - ofs] : 0;
        __syncthreads();
        s[tid] += t;
        __syncthreads();
    }
    const int excl = s[tid] - v;
    if (tid < NBKT) {
        boff[tid] = excl;
        gcur[tid] = excl;
    }
    if (tid == NBKT - 1) {
        boff[NBKT] = s[tid];
        rs[NNODES] = NEDGES;
    }
}

// ---------- megaA: MFMA dual GEMM1 (even blocks) + edge binning (odd) ----------
__global__ __launch_bounds__(256) void megaA_kernel(
    const float* __restrict__ x, const ushort* __restrict__ wt,
    const float* __restrict__ b1, ushort* __restrict__ hbf,
    uchar* __restrict__ xnf8, const int* __restrict__ src,
    const int* __restrict__ dst, int* __restrict__ gcur,
    uint* __restrict__ pairbuf) {
    __shared__ uint4 sWq[4096];  // 64 KB: [2][128 cols][16 chunks of 8 bf16]
    const int bid = blockIdx.x;
    const int tid = threadIdx.x;

    if (bid & 1) {
        // ---------- bin branch: 2048 edges, packed (src<<9 | ldst) ----------
        int* ib = (int*)sWq;
        int* lhist = ib;
        int* lofs = ib + 256;
        int* gbl = ib + 512;
        int* lcur = ib + 768;
        const int t = bid >> 1;
        const int ebase = t * 2048;
        const int n = min(2048, NEDGES - ebase);
        const int nv4 = n >> 2;
        lhist[tid] = 0;
        lcur[tid] = 0;
        __syncthreads();
        int4 sv[2], dv[2];
#pragma unroll
        for (int u = 0; u < 2; ++u) {
            const int i4 = tid + 256 * u;
            if (i4 < nv4) {
                sv[u] = ((const int4*)(src + ebase))[i4];
                dv[u] = ((const int4*)(dst + ebase))[i4];
                atomicAdd(&lhist[dv[u].x >> 9], 1);
                atomicAdd(&lhist[dv[u].y >> 9], 1);
                atomicAdd(&lhist[dv[u].z >> 9], 1);
                atomicAdd(&lhist[dv[u].w >> 9], 1);
            }
        }
        __syncthreads();
        const int v = lhist[tid];
        lofs[tid] = v;
        __syncthreads();
        for (int ofs = 1; ofs < 256; ofs <<= 1) {
            int tv = (tid >= ofs) ? lofs[tid - ofs] : 0;
            __syncthreads();
            lofs[tid] += tv;
            __syncthreads();
        }
        if (tid < NBKT && v > 0) gbl[tid] = atomicAdd(&gcur[tid], v);
        __syncthreads();
#pragma unroll
        for (int u = 0; u < 2; ++u) {
            const int i4 = tid + 256 * u;
            if (i4 < nv4) {
                const int ss[4] = {sv[u].x, sv[u].y, sv[u].z, sv[u].w};
                const int dd[4] = {dv[u].x, dv[u].y, dv[u].z, dv[u].w};
#pragma unroll
                for (int j = 0; j < 4; ++j) {
                    const int b = dd[j] >> 9;
                    const int p = atomicAdd(&lcur[b], 1);
                    pairbuf[gbl[b] + p] =
                        ((uint)ss[j] << 9) | ((uint)dd[j] & 511u);
                }
            }
        }
        return;
    }

    // ---------- GEMM branch ----------
    const int g = bid >> 1;  // 0..NGB-1
#pragma unroll
    for (int i = 0; i < 16; ++i) {
        const int cid = tid + 256 * i;
        const int kc = cid & 15;
        const int c = (cid >> 4) & 127;
        const int wsel = cid >> 11;
        sWq[wsel * 2048 + c * 16 + (kc ^ (c & 15))] = *(const uint4*)&wt[cid * 8];
    }
    const int w = tid >> 6;   // wave 0..3
    const int l = tid & 63;
    const int lg = l >> 4;
    const int lr = l & 15;
    const int rowbase = g * 64;
    const int arow = min(rowbase + w * 16 + lr, NNODES - 1);
    const float* xrow = x + (size_t)arow * 128;
    short8 ahi[4], alo[4];
#pragma unroll
    for (int ks = 0; ks < 4; ++ks) {
        const float4 va = *(const float4*)&xrow[ks * 32 + lg * 8];
        const float4 vb = *(const float4*)&xrow[ks * 32 + lg * 8 + 4];
        const float vv[8] = {va.x, va.y, va.z, va.w, vb.x, vb.y, vb.z, vb.w};
        short8 h8, l8;
#pragma unroll
        for (int j = 0; j < 8; ++j) {
            const ushort hu = bf16_rne(vv[j]);
            h8[j] = (short)hu;
            l8[j] = (short)bf16_rne(vv[j] - __uint_as_float((uint)hu << 16));
        }
        ahi[ks] = h8;
        alo[ks] = l8;
    }
    __syncthreads();

#pragma unroll
    for (int wsel = 0; wsel < 2; ++wsel) {
#pragma unroll
        for (int ct = 0; ct < 8; ++ct) {
            f32x4 acc;
            if (wsel == 0) {
                const float bv = b1[ct * 16 + lr];
                acc = (f32x4){bv, bv, bv, bv};
            } else {
                acc = (f32x4){0.0f, 0.0f, 0.0f, 0.0f};
            }
            const int cbase = wsel * 2048 + (ct * 16 + lr) * 16;
#pragma unroll
            for (int ks = 0; ks < 4; ++ks) {
                const short8 bf =
                    *(const short8*)&sWq[cbase + ((4 * ks + lg) ^ lr)];
                acc = __builtin_amdgcn_mfma_f32_16x16x32_bf16(ahi[ks], bf, acc, 0, 0, 0);
                acc = __builtin_amdgcn_mfma_f32_16x16x32_bf16(alo[ks], bf, acc, 0, 0, 0);
            }
#pragma unroll
            for (int r_ = 0; r_ < 4; ++r_) {
                const int orow = rowbase + w * 16 + lg * 4 + r_;
                if (orow < NNODES) {
                    if (wsel == 0)
                        hbf[(size_t)orow * 128 + ct * 16 + lr] = bf16_rne(acc[r_]);
                    else
                        xnf8[(size_t)orow * 128 + ct * 16 + lr] = f32_to_fp8(acc[r_]);
                }
            }
        }
    }
}

// ---------- phase B: per-bucket CSR finalize (deg/invd/rs/ebuf) ----------
__global__ __launch_bounds__(256) void bucket_kernel(const uint* __restrict__ pairbuf,
                                                     const int* __restrict__ boff,
                                                     int* __restrict__ rs,
                                                     float* __restrict__ invd,
                                                     int* __restrict__ ebuf) {
    __shared__ int ndeg[512];
    __shared__ int nofs[512];
    __shared__ int lcur[512];
    __shared__ int sps[256];
    const int b = blockIdx.x;
    const int tid = threadIdx.x;
    const int nb = b << 9;
    const int ln = min(512, NNODES - nb);
    const int base = boff[b];
    const int cnt = boff[b + 1] - base;
    for (int i = tid; i < 512; i += 256) {
        ndeg[i] = 0;
        lcur[i] = 0;
    }
    __syncthreads();
    for (int i = tid; i < cnt; i += 256) {
        atomicAdd(&ndeg[pairbuf[base + i] & 511u], 1);
    }
    __syncthreads();
    for (int nidx = tid; nidx < ln; nidx += 256)
        invd[nb + nidx] = 1.0f / fmaxf((float)ndeg[nidx], 1.0f);
    const int a0 = ndeg[2 * tid];
    const int a1 = ndeg[2 * tid + 1];
    sps[tid] = a0 + a1;
    __syncthreads();
    for (int ofs = 1; ofs < 256; ofs <<= 1) {
        int t = (tid >= ofs) ? sps[tid - ofs] : 0;
        __syncthreads();
        sps[tid] += t;
        __syncthreads();
    }
    const int excl = sps[tid] - (a0 + a1);
    nofs[2 * tid] = excl;
    nofs[2 * tid + 1] = excl + a0;
    __syncthreads();
    for (int nidx = tid; nidx < ln; nidx += 256) rs[nb + nidx] = base + nofs[nidx];
    for (int i = tid; i < cnt; i += 256) {
        const uint e = pairbuf[base + i];
        const int nn = (int)(e & 511u);
        const int p = atomicAdd(&lcur[nn], 1);
        ebuf[base + nofs[nn] + p] = (int)(e >> 9);
    }
}

// ---------- layer-2 dual GEMM (MFMA): out = h@W2s + b2 (f32) ; hn fp8 ----------
__global__ __launch_bounds__(256) void gemm2_dual_kernel(
    const ushort* __restrict__ hbf, const ushort* __restrict__ wt2,
    const float* __restrict__ b2, float* __restrict__ out,
    uchar* __restrict__ hnf8) {
    __shared__ uint4 sWq[2048];  // 32 KB
    const int tid = threadIdx.x;
#pragma unroll
    for (int i = 0; i < 8; ++i) {
        const int cid = tid + 256 * i;
        const int kc = cid & 15;
        const int c = cid >> 4;
        sWq[c * 16 + (kc ^ (c & 15))] = *(const uint4*)&wt2[cid * 8];
    }
    const int w = tid >> 6;
    const int l = tid & 63;
    const int lg = l >> 4;
    const int lr = l & 15;
    const int rowbase = blockIdx.x * 64;
    const int arow = min(rowbase + w * 16 + lr, NNODES - 1);
    const ushort* hrow = hbf + (size_t)arow * 128;
    short8 a[4];
#pragma unroll
    for (int ks = 0; ks < 4; ++ks) a[ks] = *(const short8*)&hrow[ks * 32 + lg * 8];
    __syncthreads();

#pragma unroll
    for (int ct = 0; ct < 8; ++ct) {
        f32x4 acc;
        if (ct < 4) {
            const float bv = b2[ct * 16 + lr];
            acc = (f32x4){bv, bv, bv, bv};
        } else {
            acc = (f32x4){0.0f, 0.0f, 0.0f, 0.0f};
        }
        const int cbase = (ct * 16 + lr) * 16;
#pragma unroll
        for (int ks = 0; ks < 4; ++ks) {
            const short8 bf = *(const short8*)&sWq[cbase + ((4 * ks + lg) ^ lr)];
            acc = __builtin_amdgcn_mfma_f32_16x16x32_bf16(a[ks], bf, acc, 0, 0, 0);
        }
#pragma unroll
        for (int r_ = 0; r_ < 4; ++r_) {
            const int orow = rowbase + w * 16 + lg * 4 + r_;
            if (orow < NNODES) {
                if (ct < 4)
                    out[(size_t)orow * 64 + ct * 16 + lr] = acc[r_];
                else
                    hnf8[(size_t)orow * 64 + (ct - 4) * 16 + lr] = f32_to_fp8(acc[r_]);
            }
        }
    }
}

// ---------- layer-1 aggregation: fp8 gather, 32-lane group per node ----------
__global__ __launch_bounds__(256) void agg1_kernel(const int* __restrict__ rs,
                                                   const int* __restrict__ ebuf,
                                                   const float* __restrict__ invd,
                                                   const uchar* __restrict__ xnf8,
                                                   ushort* __restrict__ hbf) {
    const int node = blockIdx.x * 8 + (threadIdx.x >> 5);
    if (node >= NNODES) return;
    const int lane = threadIdx.x & 31;
    const int beg = rs[node];
    const int end = rs[node + 1];
    const uint* fp = (const uint*)xnf8 + lane;  // row stride 32 uints (128 B)
    float a0 = 0.0f, a1 = 0.0f, a2 = 0.0f, a3 = 0.0f;
    int i = beg;
    for (; i + 3 < end; i += 4) {
#pragma unroll
        for (int u = 0; u < 4; ++u) {
            const uint pk = fp[(size_t)ebuf[i + u] * 32];
            const float2 lo = fp8_lo2(pk);
            const float2 hi = fp8_hi2(pk);
            a0 += lo.x; a1 += lo.y; a2 += hi.x; a3 += hi.y;
        }
    }
    for (; i < end; ++i) {
        const uint pk = fp[(size_t)ebuf[i] * 32];
        const float2 lo = fp8_lo2(pk);
        const float2 hi = fp8_hi2(pk);
        a0 += lo.x; a1 += lo.y; a2 += hi.x; a3 += hi.y;
    }
    const float w = invd[node];
    uint* hp = (uint*)hbf + (size_t)node * 64 + lane * 2;
    uint2 hv = *(uint2*)hp;
    float2 h0 = unpack_bf2(hv.x);
    float2 h1 = unpack_bf2(hv.y);
    h0.x = fmaxf(fmaf(w, a0, h0.x), 0.0f);
    h0.y = fmaxf(fmaf(w, a1, h0.y), 0.0f);
    h1.x = fmaxf(fmaf(w, a2, h1.x), 0.0f);
    h1.y = fmaxf(fmaf(w, a3, h1.y), 0.0f);
    hv.x = pack_bf2(h0.x, h0.y);
    hv.y = pack_bf2(h1.x, h1.y);
    *(uint2*)hp = hv;
}

// ---------- layer-2 aggregation: fp8 gather, 32-lane group per node ----------
__global__ __launch_bounds__(256) void agg2_kernel(const int* __restrict__ rs,
                                                   const int* __restrict__ ebuf,
                                                   const float* __restrict__ invd,
                                                   const uchar* __restrict__ hnf8,
                                                   float* __restrict__ out) {
    const int node = blockIdx.x * 8 + (threadIdx.x >> 5);
    if (node >= NNODES) return;
    const int lane = threadIdx.x & 31;
    const int beg = rs[node];
    const int end = rs[node + 1];
    const ushort* fp = (const ushort*)hnf8 + lane;  // row stride 32 ushorts (64 B)
    float a0 = 0.0f, a1 = 0.0f;
    int i = beg;
    for (; i + 3 < end; i += 4) {
#pragma unroll
        for (int u = 0; u < 4; ++u) {
            const uint pk = (uint)fp[(size_t)ebuf[i + u] * 32];
            const float2 v = fp8_lo2(pk);
            a0 += v.x; a1 += v.y;
        }
    }
    for (; i < end; ++i) {
        const uint pk = (uint)fp[(size_t)ebuf[i] * 32];
        const float2 v = fp8_lo2(pk);
        a0 += v.x; a1 += v.y;
    }
    const float w = invd[node];
    float2* op = (float2*)&out[(size_t)node * 64 + lane * 2];
    float2 ov = *op;
    ov.x = fmaf(w, a0, ov.x);
    ov.y = fmaf(w, a1, ov.y);
    *op = ov;
}

extern "C" void kernel_launch(void* const* d_in, const int* in_sizes, int n_in,
                              void* d_out, int out_size, void* d_ws, size_t ws_size,
                              hipStream_t stream) {
    const float* x   = (const float*)d_in[0];
    const int*   ei  = (const int*)d_in[1];
    const float* W1s = (const float*)d_in[2];
    const float* W1n = (const float*)d_in[3];
    const float* b1  = (const float*)d_in[4];
    const float* W2s = (const float*)d_in[5];
    const float* W2n = (const float*)d_in[6];
    const float* b2  = (const float*)d_in[7];
    float* out = (float*)d_out;

    const int* src = ei;           // edge_index row 0
    const int* dst = ei + NEDGES;  // edge_index row 1

    // workspace carve-up (word offsets)
    int* w = (int*)d_ws;
    int*    bhist   = w;                        // 256
    int*    boff    = w + 256;                  // 256 (need 197)
    int*    gcur    = w + 512;                  // 256
    int*    rs      = w + 768;                  // 100,001 (pad to 100,864)
    float*  invd    = (float*)(w + 100864);     // 100,000
    int*    ebuf    = w + 200864;               // 3,200,000
    uint*   pairbuf = (uint*)(w + 3400864);     // 3,200,000 packed edges
    uchar*  xnf8    = (uchar*)(w + 6600864);    // N*128 fp8 (3.2M words)
    ushort* hbf     = (ushort*)(w + 9800864);   // N*128 bf16 (6.4M words)
    ushort* wtbuf   = (ushort*)(w + 16200864);  // 49,152 ushorts
    uchar*  hnf8    = xnf8;  // reuse after agg1 (needs N*64 fp8)

    hipMemsetAsync(bhist, 0, 256 * sizeof(int), stream);
    histprep_kernel<<<704, 256, 0, stream>>>(dst, bhist, W1s, W1n, W2s, W2n, wtbuf);
    scan_bkt<<<1, 256, 0, stream>>>(bhist, boff, gcur, rs);

    // layer-1 dual MFMA GEMM fused 1:1 with edge binning
    megaA_kernel<<<2 * NTILES2, 256, 0, stream>>>(x, wtbuf, b1, hbf, xnf8, src, dst,
                                                  gcur, pairbuf);
    bucket_kernel<<<NBKT, 256, 0, stream>>>(pairbuf, boff, rs, invd, ebuf);

    agg1_kernel<<<NNODES / 8, 256, 0, stream>>>(rs, ebuf, invd, xnf8, hbf);

    gemm2_dual_kernel<<<NGB, 256, 0, stream>>>(hbf, wtbuf + 32768, b2, out, hnf8);
    agg2_kernel<<<NNODES / 8, 256, 0, stream>>>(rs, ebuf, invd, hnf8, out);
}